// Round 5
// baseline (397.138 us; speedup 1.0000x reference)
//
#include <hip/hip_runtime.h>
#include <hip/hip_bf16.h>

typedef __hip_bfloat16 bf16;
typedef __attribute__((ext_vector_type(8))) short short8;   // 8 bf16 = 4 VGPR
typedef __attribute__((ext_vector_type(4))) float f32x4;

#define HWP 3136
#define WD 56
#define PW 58          // padded width (1-px zero border)
#define PADP 3364      // 58*58
#define CC 128
#define MIDM 32
#define OGN 512
#define NB 4

// workspace offsets in FLOAT units (all 16B-aligned)
enum : int {
  OFF_FLAG = 0,                          // [4] flag[0]: 1=bf16 inputs
  OFF_W2F  = 4,                          // fp32 [o][m] 512x32 (for stats)
  OFF_SC2  = OFF_W2F + OGN*MIDM,         // [32]
  OFF_SH2  = OFF_SC2 + MIDM,             // [32]
  OFF_B1F  = OFF_SH2 + MIDM,             // [32]
  OFF_B2F  = OFF_B1F + MIDM,             // [512]
  OFF_GNG  = OFF_B2F + OGN,              // [512]
  OFF_GNB  = OFF_GNG + OGN,              // [512]
  OFF_S1   = OFF_GNB + OGN,              // [b][32] atomics
  OFF_GRAM = OFF_S1 + NB*MIDM,           // [b][32][32] atomics
  OFF_PQ   = OFF_GRAM + NB*MIDM*MIDM,    // float2 [b][512]
  OFF_SS1  = OFF_PQ + NB*OGN*2,          // float2 [128] bn1 scale/shift
  OFF_SSV  = OFF_SS1 + CC*2,             // float2 [512] bnv scale/shift
  OFF_WKB  = OFF_SSV + OGN*2,            // bf16 [d][c] 128x128
  OFF_WVB  = OFF_WKB + CC*CC/2,          // bf16 [o][c] 512x128
  OFF_W1AB = OFF_WVB + OGN*CC/2,         // bf16 [m][c] 32x128
  OFF_W1BB = OFF_W1AB + MIDM*CC/2,       // bf16 [m][c] 32x128
  OFF_W2B  = OFF_W1BB + MIDM*CC/2,       // bf16 [o][m] 512x32
  OFF_HQT  = OFF_W2B + OGN*MIDM/2,       // bf16 [b][pix][m]
  OFF_GKT  = OFF_HQT + NB*HWP*MIDM/2,    // bf16 [b][pix][m]
  OFF_VT   = OFF_GKT + NB*HWP*MIDM/2,    // bf16 [b][pp PADP][o]; becomes P*v; zero border
  OFF_WQ   = OFF_VT + NB*PADP*OGN/2,     // bf16 [b][pp PADP][co]  w = sum_gc Q*v; zero border
  OFF_WSUM = OFF_WQ + NB*PADP*CC/2,      // bf16 [b][pix][co] 3x3 box of w
  OFF_R1   = OFF_WSUM + NB*HWP*CC/2,     // union region
  OFF_XT   = OFF_R1,                     // bf16 [b][pix][c]    (phase 1)
  OFF_HS   = OFF_R1,                     // bf16 [b][p][pix][m] (phase 2)
  WS_TOTAL = OFF_R1 + NB*9*HWP*MIDM/2    // ~32 MB total
};

__device__ __forceinline__ float b2f(unsigned short u) {
  bf16 h; *(unsigned short*)&h = u; return __bfloat162float(h);
}
__device__ __forceinline__ unsigned short f2b(float f) {
  bf16 h = __float2bfloat16(f); return *(unsigned short*)&h;
}
__device__ __forceinline__ float ldmix(const void* p, size_t i, bool isbf) {
  return isbf ? __bfloat162float(((const bf16*)p)[i]) : ((const float*)p)[i];
}
__device__ __forceinline__ f32x4 mfma16(short8 a, short8 b, f32x4 c) {
  return __builtin_amdgcn_mfma_f32_16x16x32_bf16(a, b, c, 0, 0, 0);
}

// ---- dtype detector ----
__global__ __launch_bounds__(256) void k_detect(const unsigned short* __restrict__ xr,
                                                float* __restrict__ ws) {
  __shared__ int bad;
  if (threadIdx.x == 0) bad = 0;
  __syncthreads();
  int cnt = 0;
  for (int i = threadIdx.x; i < 16384; i += 256) {
    int e = (xr[i] >> 7) & 0xFF;
    if (e >= 141) cnt++;
  }
  atomicAdd(&bad, cnt);
  __syncthreads();
  if (threadIdx.x == 0) ws[OFF_FLAG] = (bad < 64) ? 1.f : 0.f;
}

// ---- zero padded regions (vt_pad + wq_pad, contiguous) ----
__global__ __launch_bounds__(256) void k_zero(float* __restrict__ ws) {
  const int n4 = (NB*PADP*OGN/2 + NB*PADP*CC/2) / 4;
  int i = blockIdx.x*256 + threadIdx.x;
  float4* dst = (float4*)(ws + OFF_VT);
  if (i < n4) dst[i] = make_float4(0.f, 0.f, 0.f, 0.f);
}

// ---- params: fold BN, cast weights to bf16, zero accumulators ----
__global__ __launch_bounds__(256) void k_prep(
    const void* __restrict__ Wk,
    const void* __restrict__ bn1_g, const void* __restrict__ bn1_b,
    const void* __restrict__ bn1_m, const void* __restrict__ bn1_v,
    const void* __restrict__ W1, const void* __restrict__ b1,
    const void* __restrict__ bn2_g, const void* __restrict__ bn2_b,
    const void* __restrict__ bn2_m, const void* __restrict__ bn2_v,
    const void* __restrict__ W2, const void* __restrict__ b2,
    const void* __restrict__ gn_g, const void* __restrict__ gn_b,
    const void* __restrict__ Wv,
    const void* __restrict__ bnv_g, const void* __restrict__ bnv_b,
    const void* __restrict__ bnv_m, const void* __restrict__ bnv_v,
    float* __restrict__ ws) {
  const bool isbf = ws[OFF_FLAG] > 0.5f;
  int tid = blockIdx.x * blockDim.x + threadIdx.x;
  int stride = gridDim.x * blockDim.x;
  unsigned short* wkb = (unsigned short*)(ws + OFF_WKB);
  unsigned short* wvb = (unsigned short*)(ws + OFF_WVB);
  unsigned short* w1ab = (unsigned short*)(ws + OFF_W1AB);
  unsigned short* w1bb = (unsigned short*)(ws + OFF_W1BB);
  unsigned short* w2b = (unsigned short*)(ws + OFF_W2B);
  float2* ss1 = (float2*)(ws + OFF_SS1);
  float2* ssv = (float2*)(ws + OFF_SSV);
  for (int i = tid; i < CC*CC; i += stride) wkb[i] = f2b(ldmix(Wk, i, isbf));
  for (int i = tid; i < OGN*CC; i += stride) wvb[i] = f2b(ldmix(Wv, i, isbf));
  for (int i = tid; i < MIDM*CC; i += stride) {
    int m = i / CC, c = i % CC;
    w1ab[i] = f2b(ldmix(W1, (size_t)m*(2*CC) + c, isbf));
    w1bb[i] = f2b(ldmix(W1, (size_t)m*(2*CC) + CC + c, isbf));
  }
  for (int i = tid; i < OGN*MIDM; i += stride) {
    float w = ldmix(W2, i, isbf);
    ws[OFF_W2F + i] = w;
    w2b[i] = f2b(w);
  }
  for (int i = tid; i < CC; i += stride) {
    float s = ldmix(bn1_g, i, isbf) / sqrtf(ldmix(bn1_v, i, isbf) + 1e-5f);
    ss1[i] = make_float2(s, ldmix(bn1_b, i, isbf) - ldmix(bn1_m, i, isbf) * s);
  }
  for (int i = tid; i < MIDM; i += stride) {
    float s = ldmix(bn2_g, i, isbf) / sqrtf(ldmix(bn2_v, i, isbf) + 1e-5f);
    ws[OFF_SC2 + i] = s;
    ws[OFF_SH2 + i] = ldmix(bn2_b, i, isbf) - ldmix(bn2_m, i, isbf) * s;
    ws[OFF_B1F + i] = ldmix(b1, i, isbf);
  }
  for (int i = tid; i < OGN; i += stride) {
    float s = ldmix(bnv_g, i, isbf) / sqrtf(ldmix(bnv_v, i, isbf) + 1e-5f);
    ssv[i] = make_float2(s, ldmix(bnv_b, i, isbf) - ldmix(bnv_m, i, isbf) * s);
    ws[OFF_B2F + i] = ldmix(b2, i, isbf);
    ws[OFF_GNG + i] = ldmix(gn_g, i, isbf);
    ws[OFF_GNB + i] = ldmix(gn_b, i, isbf);
  }
  for (int i = tid; i < NB*MIDM; i += stride) ws[OFF_S1 + i] = 0.f;
  for (int i = tid; i < NB*MIDM*MIDM; i += stride) ws[OFF_GRAM + i] = 0.f;
}

// ---- x -> xt[b][pix][c] bf16, LDS-tiled transpose. grid (98,4) ----
__global__ __launch_bounds__(256) void k_tx(const void* __restrict__ x,
                                            float* __restrict__ ws) {
  __shared__ unsigned short tile[32*130];
  const bool isbf = ws[OFF_FLAG] > 0.5f;
  int b = blockIdx.y, pix0 = blockIdx.x * 32;
#pragma unroll
  for (int k = 0; k < 16; k++) {
    int idx = threadIdx.x + k*256;
    int c = idx >> 5, pl = idx & 31;
    tile[pl*130 + c] = f2b(ldmix(x, ((size_t)b*CC + c)*HWP + pix0 + pl, isbf));
  }
  __syncthreads();
  unsigned short* xt = (unsigned short*)(ws + OFF_XT);
#pragma unroll
  for (int k = 0; k < 16; k++) {
    int idx = threadIdx.x + k*256;
    int c = idx & 127, pl = idx >> 7;
    xt[((size_t)b*HWP + pix0 + pl)*CC + c] = tile[pl*130 + c];
  }
}

// ---- fused: ke = relu(bn1(Wk.x)) in LDS, then hq_t/gk_t. grid (49,1,4) ----
__global__ __launch_bounds__(256, 4) void k_keq(float* __restrict__ ws) {
  __shared__ unsigned short keL[4][16][136];
  int b = blockIdx.z;
  int w = threadIdx.x >> 6, lane = threadIdx.x & 63;
  int q = lane >> 4, l16 = lane & 15;
  int pix = blockIdx.x*64 + w*16 + l16;
  const unsigned short* xt = (const unsigned short*)(ws + OFF_XT) + ((size_t)b*HWP + pix)*CC;
  short8 Bx[4];
#pragma unroll
  for (int kk = 0; kk < 4; kk++) Bx[kk] = *(const short8*)(xt + kk*32 + q*8);
  const unsigned short* wkb = (const unsigned short*)(ws + OFF_WKB);
  const float2* ss = (const float2*)(ws + OFF_SS1);
#pragma unroll
  for (int ot = 0; ot < 8; ot++) {
    int drow = ot*16 + l16;
    f32x4 c = {0.f, 0.f, 0.f, 0.f};
#pragma unroll
    for (int kk = 0; kk < 4; kk++)
      c = mfma16(*(const short8*)(wkb + (size_t)drow*CC + kk*32 + q*8), Bx[kk], c);
    int d0 = ot*16 + q*4;
    ushort4 st;
    { float2 s = ss[d0+0]; st.x = f2b(fmaxf(s.x*c[0] + s.y, 0.f)); }
    { float2 s = ss[d0+1]; st.y = f2b(fmaxf(s.x*c[1] + s.y, 0.f)); }
    { float2 s = ss[d0+2]; st.z = f2b(fmaxf(s.x*c[2] + s.y, 0.f)); }
    { float2 s = ss[d0+3]; st.w = f2b(fmaxf(s.x*c[3] + s.y, 0.f)); }
    *(ushort4*)&keL[w][l16][d0] = st;
  }
  __syncthreads();
  short8 Bk[4];
#pragma unroll
  for (int kk = 0; kk < 4; kk++) Bk[kk] = *(const short8*)&keL[w][l16][kk*32 + q*8];
  const unsigned short* w1a = (const unsigned short*)(ws + OFF_W1AB);
  const unsigned short* w1b = (const unsigned short*)(ws + OFF_W1BB);
  unsigned short* hqt = (unsigned short*)(ws + OFF_HQT) + ((size_t)b*HWP + pix)*MIDM;
  unsigned short* gkt = (unsigned short*)(ws + OFF_GKT) + ((size_t)b*HWP + pix)*MIDM;
#pragma unroll
  for (int mt = 0; mt < 2; mt++) {
    int mrow = mt*16 + l16;
    f32x4 ch = {0.f,0.f,0.f,0.f}, cg = {0.f,0.f,0.f,0.f};
#pragma unroll
    for (int kk = 0; kk < 4; kk++) {
      ch = mfma16(*(const short8*)(w1a + (size_t)mrow*CC + kk*32 + q*8), Bx[kk], ch);
      cg = mfma16(*(const short8*)(w1b + (size_t)mrow*CC + kk*32 + q*8), Bk[kk], cg);
    }
    int m0 = mt*16 + q*4;
    ushort4 sh, sg;
    sh.x = f2b(ch[0]); sh.y = f2b(ch[1]); sh.z = f2b(ch[2]); sh.w = f2b(ch[3]);
    sg.x = f2b(cg[0]); sg.y = f2b(cg[1]); sg.z = f2b(cg[2]); sg.w = f2b(cg[3]);
    *(ushort4*)(hqt + m0) = sh;
    *(ushort4*)(gkt + m0) = sg;
  }
}

// ---- v_pad[pp][o] = bnv(Wv.x) via MFMA (padded grid). grid (49,4,4) ----
__global__ __launch_bounds__(256, 4) void k_v(float* __restrict__ ws) {
  int b = blockIdx.z, by = blockIdx.y;
  int w = threadIdx.x >> 6, lane = threadIdx.x & 63;
  int q = lane >> 4, l16 = lane & 15;
  int pix = blockIdx.x*64 + w*16 + l16;
  int h0 = pix / WD, w0 = pix - h0*WD;
  int pp = (h0+1)*PW + (w0+1);
  const unsigned short* xt = (const unsigned short*)(ws + OFF_XT) + ((size_t)b*HWP + pix)*CC;
  short8 B[4];
#pragma unroll
  for (int kk = 0; kk < 4; kk++) B[kk] = *(const short8*)(xt + kk*32 + q*8);
  const unsigned short* wvb = (const unsigned short*)(ws + OFF_WVB);
  const float2* ss = (const float2*)(ws + OFF_SSV);
  unsigned short* vt = (unsigned short*)(ws + OFF_VT) + ((size_t)b*PADP + pp)*OGN;
#pragma unroll
  for (int ot = 0; ot < 8; ot++) {
    int orow = by*128 + ot*16 + l16;
    f32x4 c = {0.f, 0.f, 0.f, 0.f};
#pragma unroll
    for (int kk = 0; kk < 4; kk++)
      c = mfma16(*(const short8*)(wvb + (size_t)orow*CC + kk*32 + q*8), B[kk], c);
    int o0 = by*128 + ot*16 + q*4;
    ushort4 st;
    { float2 s = ss[o0+0]; st.x = f2b(s.x*c[0] + s.y); }
    { float2 s = ss[o0+1]; st.y = f2b(s.x*c[1] + s.y); }
    { float2 s = ss[o0+2]; st.z = f2b(s.x*c[2] + s.y); }
    { float2 s = ss[o0+3]; st.w = f2b(s.x*c[3] + s.y); }
    *(ushort4*)(vt + o0) = st;
  }
}

// ---- hs[b][p][pix][m] = relu(bn2(hq + shift(gk) + b1)). grid (13,9,4) ----
__global__ __launch_bounds__(256) void k_h(float* __restrict__ ws) {
  int b = blockIdx.z, p = blockIdx.y;
  int pix = blockIdx.x*256 + threadIdx.x;
  if (pix >= HWP) return;
  int h0 = pix / WD, w0 = pix - h0*WD;
  int nh = h0 + p/3 - 1, nw = w0 + p%3 - 1;
  bool valid = ((unsigned)nh < (unsigned)WD) && ((unsigned)nw < (unsigned)WD);
  int npix = nh*WD + nw;
  const unsigned short* hq = (const unsigned short*)(ws + OFF_HQT) + ((size_t)b*HWP + pix)*MIDM;
  const unsigned short* gk = (const unsigned short*)(ws + OFF_GKT) + ((size_t)b*HWP + npix)*MIDM;
  unsigned short* hd = (unsigned short*)(ws + OFF_HS) + ((size_t)((b*9 + p))*HWP + pix)*MIDM;
  float hv[MIDM];
#pragma unroll
  for (int k = 0; k < 4; k++) {
    short8 t = *(const short8*)(hq + k*8);
#pragma unroll
    for (int j = 0; j < 8; j++) hv[k*8+j] = b2f((unsigned short)t[j]);
  }
  if (valid) {
#pragma unroll
    for (int k = 0; k < 4; k++) {
      short8 t = *(const short8*)(gk + k*8);
#pragma unroll
      for (int j = 0; j < 8; j++) hv[k*8+j] += b2f((unsigned short)t[j]);
    }
  }
#pragma unroll
  for (int k = 0; k < 8; k++) {
    ushort4 st;
    int m = k*4;
    st.x = f2b(fmaxf(ws[OFF_SC2+m+0]*(hv[m+0] + ws[OFF_B1F+m+0]) + ws[OFF_SH2+m+0], 0.f));
    st.y = f2b(fmaxf(ws[OFF_SC2+m+1]*(hv[m+1] + ws[OFF_B1F+m+1]) + ws[OFF_SH2+m+1], 0.f));
    st.z = f2b(fmaxf(ws[OFF_SC2+m+2]*(hv[m+2] + ws[OFF_B1F+m+2]) + ws[OFF_SH2+m+2], 0.f));
    st.w = f2b(fmaxf(ws[OFF_SC2+m+3]*(hv[m+3] + ws[OFF_B1F+m+3]) + ws[OFF_SH2+m+3], 0.f));
    *(ushort4*)(hd + m) = st;
  }
}

// ---- Gram + S1 via MFMA, LDS-staged coalesced loads. grid (111,4) ----
__global__ __launch_bounds__(256) void k_gram(float* __restrict__ ws) {
  __shared__ unsigned short tile[256][40];   // 40-ushort stride: 16B-aligned rows
  int b = blockIdx.y;
  int i0 = blockIdx.x*256;
  const unsigned short* hsb = (const unsigned short*)(ws + OFF_HS) + (size_t)b*9*HWP*MIDM;
  const short8 zero8 = {0,0,0,0,0,0,0,0};
#pragma unroll
  for (int pass = 0; pass < 4; pass++) {
    int row = pass*64 + (threadIdx.x >> 2);
    int col = (threadIdx.x & 3)*8;
    int i = i0 + row;
    short8 val = (i < 9*HWP) ? *(const short8*)(hsb + (size_t)i*MIDM + col) : zero8;
    *(short8*)&tile[row][col] = val;
  }
  __syncthreads();
  int w = threadIdx.x >> 6, lane = threadIdx.x & 63;
  int q = lane >> 4, l16 = lane & 15;
  f32x4 gLL = {0,0,0,0}, gLH = {0,0,0,0}, gHH = {0,0,0,0};
  f32x4 sL = {0,0,0,0}, sH = {0,0,0,0};
  short8 ones;
#pragma unroll
  for (int j = 0; j < 8; j++) ones[j] = (short)0x3F80;
#pragma unroll
  for (int c = 0; c < 2; c++) {
    int r0 = w*64 + c*32 + q*8;
    short8 alo, ahi;
#pragma unroll
    for (int j = 0; j < 8; j++) {
      alo[j] = (short)tile[r0 + j][l16];
      ahi[j] = (short)tile[r0 + j][l16 + 16];
    }
    gLL = mfma16(alo, alo, gLL);
    gLH = mfma16(alo, ahi, gLH);
    gHH = mfma16(ahi, ahi, gHH);
    sL = mfma16(alo, ones, sL);
    sH = mfma16(ahi, ones, sH);
  }
  float* G = ws + OFF_GRAM + b*MIDM*MIDM;
#pragma unroll
  for (int r = 0; r < 4; r++) {
    atomicAdd(&G[(q*4 + r)*MIDM + l16],           gLL[r]);
    atomicAdd(&G[(q*4 + r)*MIDM + 16 + l16],      gLH[r]);
    atomicAdd(&G[(16 + l16)*MIDM + q*4 + r],      gLH[r]);   // HL = LH^T
    atomicAdd(&G[(16 + q*4 + r)*MIDM + 16 + l16], gHH[r]);
  }
  if (l16 == 0) {
#pragma unroll
    for (int r = 0; r < 4; r++) {
      atomicAdd(&ws[OFF_S1 + b*MIDM + q*4 + r],      sL[r]);
      atomicAdd(&ws[OFF_S1 + b*MIDM + 16 + q*4 + r], sH[r]);
    }
  }
}

// ---- GN stats -> PQ float2 per (b,o). grid (4) x 512 ----
__global__ __launch_bounds__(512) void k_stats(float* __restrict__ ws) {
  __shared__ float Gs[MIDM*MIDM], S1s[MIDM], saS[OGN], sqS[OGN], muS[128], invS[128];
  int b = blockIdx.x, o = threadIdx.x;
  Gs[o] = ws[OFF_GRAM + b*MIDM*MIDM + o];
  Gs[512 + o] = ws[OFF_GRAM + b*MIDM*MIDM + 512 + o];
  if (o < MIDM) S1s[o] = ws[OFF_S1 + b*MIDM + o];
  __syncthreads();
  float w2[MIDM];
#pragma unroll
  for (int m = 0; m < MIDM; m++) w2[m] = ws[OFF_W2F + o*MIDM + m];
  float dotS = 0.f;
#pragma unroll
  for (int m = 0; m < MIDM; m++) dotS += w2[m] * S1s[m];
  float quad = 0.f;
  for (int a = 0; a < MIDM; a++) {
    float t = 0.f;
#pragma unroll
    for (int c = 0; c < MIDM; c++) t += Gs[a*MIDM + c] * w2[c];
    quad += w2[a] * t;
  }
  float b2o = ws[OFF_B2F + o];
  const float M = 9.f * HWP;
  saS[o] = dotS + b2o * M;
  sqS[o] = quad + 2.f*b2o*dotS + b2o*b2o*M;
  __syncthreads();
  if (o < 128) {
    float sa = saS[4*o] + saS[4*o+1] + saS[4*o+2] + saS[4*o+3];
    float sq = sqS[4*o] + sqS[4*o+1] + sqS[4*o+2] + sqS[4*o+3];
    const float invN = 1.f / (4.f * M);
    float mu = sa * invN;
    float var = sq * invN - mu*mu;
    muS[o] = mu;
    invS[o] = 1.f / sqrtf(var + 1e-5f);
  }
  __syncthreads();
  int co = o >> 2;
  float alpha = ws[OFF_GNG + o] * invS[co];
  ((float2*)(ws + OFF_PQ))[b*OGN + o] =
      make_float2(alpha, alpha*b2o + ws[OFF_GNB + o] - muS[co]*alpha);
}

// ---- vt_pad <- P*vt_pad; wq_pad[pp][co] = sum_gc Q*v. grid (784) ----
__global__ __launch_bounds__(256) void k_vpq(float* __restrict__ ws) {
  int t = blockIdx.x*256 + threadIdx.x;
  int pixg = t >> 4;
  int b = pixg / HWP, pix = pixg - b*HWP;
  int oc = (t & 15) * 32;
  int h0 = pix / WD, w0 = pix - h0*WD;
  int pp = (h0+1)*PW + (w0+1);
  unsigned short* vt = (unsigned short*)(ws + OFF_VT) + ((size_t)b*PADP + pp)*OGN + oc;
  const float2* pq = (const float2*)(ws + OFF_PQ) + b*OGN + oc;
  unsigned short* wq = (unsigned short*)(ws + OFF_WQ) + ((size_t)b*PADP + pp)*CC + (oc >> 2);
  float wacc[8];
#pragma unroll
  for (int j = 0; j < 8; j++) wacc[j] = 0.f;
#pragma unroll
  for (int ch = 0; ch < 4; ch++) {
    short8 vv = *(short8*)(vt + ch*8);
#pragma unroll
    for (int j = 0; j < 8; j++) {
      int oo = ch*8 + j;
      float v = b2f((unsigned short)vv[j]);
      float2 P = pq[oo];
      wacc[oo >> 2] += P.y * v;
      vv[j] = (short)f2b(P.x * v);
    }
    *(short8*)(vt + ch*8) = vv;
  }
  short8 st;
#pragma unroll
  for (int j = 0; j < 8; j++) st[j] = (short)f2b(wacc[j]);
  *(short8*)wq = st;
}

// ---- wsum[pix][co] = 3x3 box of wq_pad (unconditional). grid (196) ----
__global__ __launch_bounds__(256) void k_wbox(float* __restrict__ ws) {
  int t = blockIdx.x*256 + threadIdx.x;
  int pixg = t >> 2;
  int b = pixg / HWP, pix = pixg - b*HWP;
  int c0 = (t & 3) * 32;
  int h0 = pix / WD, w0 = pix - h0*WD;
  int pp0 = (h0+1)*PW + (w0+1);
  const unsigned short* wq = (const unsigned short*)(ws + OFF_WQ) + (size_t)b*PADP*CC + c0;
  float acc[32];
#pragma unroll
  for (int j = 0; j < 32; j++) acc[j] = 0.f;
#pragma unroll
  for (int p = 0; p < 9; p++) {
    int npp = pp0 + (p/3 - 1)*PW + (p%3 - 1);
    const unsigned short* row = wq + (size_t)npp*CC;
#pragma unroll
    for (int ch = 0; ch < 4; ch++) {
      short8 vv = *(const short8*)(row + ch*8);
#pragma unroll
      for (int j = 0; j < 8; j++) acc[ch*8+j] += b2f((unsigned short)vv[j]);
    }
  }
  unsigned short* dst = (unsigned short*)(ws + OFF_WSUM) + ((size_t)b*HWP + pix)*CC + c0;
#pragma unroll
  for (int ch = 0; ch < 4; ch++) {
    short8 st;
#pragma unroll
    for (int j = 0; j < 8; j++) st[j] = (short)f2b(acc[ch*8+j]);
    *(short8*)(dst + ch*8) = st;
  }
}

// ---- epilogue, branch-free: out = wsum + sum_p sum_o (W2.h)*(P*v_pad).
//     grid (196,4,4), block 64 (1 wave, 16 pix x 128 o) ----
__global__ __launch_bounds__(64, 4) void k_out(const float* __restrict__ ws,
                                               void* __restrict__ outp) {
  int b = blockIdx.z, by = blockIdx.y;
  int lane = threadIdx.x;
  int q = lane >> 4, l16 = lane & 15;
  int pix = blockIdx.x*16 + l16;
  int h0 = pix / WD, w0 = pix - h0*WD;
  int pp0 = (h0+1)*PW + (w0+1);
  const bool isbf = ws[OFF_FLAG] > 0.5f;
  const unsigned short* w2b = (const unsigned short*)(ws + OFF_W2B);
  short8 A[8];
#pragma unroll
  for (int ot = 0; ot < 8; ot++) {
    int orow = by*128 + ot*16 + l16;
    A[ot] = *(const short8*)(w2b + (size_t)orow*MIDM + q*8);
  }
  const unsigned short* vtp = (const unsigned short*)(ws + OFF_VT) + (size_t)b*PADP*OGN
                              + by*128 + q*4;
  const unsigned short* hsb = (const unsigned short*)(ws + OFF_HS) + (size_t)b*9*HWP*MIDM;
  const unsigned short* wsum = (const unsigned short*)(ws + OFF_WSUM) + ((size_t)b*HWP + pix)*CC;
  float acc[8];
#pragma unroll
  for (int ot = 0; ot < 8; ot++) acc[ot] = b2f(wsum[by*32 + ot*4 + q]);
#pragma unroll
  for (int p = 0; p < 9; p++) {
    int npp = pp0 + (p/3 - 1)*PW + (p%3 - 1);
    short8 B = *(const short8*)(hsb + ((size_t)p*HWP + pix)*MIDM + q*8);
    const unsigned short* vrow = vtp + (size_t)npp*OGN;
#pragma unroll
    for (int ot = 0; ot < 8; ot++) {
      f32x4 c = {0.f, 0.f, 0.f, 0.f};
      c = mfma16(A[ot], B, c);
      ushort4 vv = *(const ushort4*)(vrow + ot*16);
      acc[ot] += c[0]*b2f(vv.x) + c[1]*b2f(vv.y) + c[2]*b2f(vv.z) + c[3]*b2f(vv.w);
    }
  }
#pragma unroll
  for (int ot = 0; ot < 8; ot++) {
    int co = by*32 + ot*4 + q;
    size_t oidx = ((size_t)b*128 + co)*HWP + pix;
    if (isbf) ((unsigned short*)outp)[oidx] = f2b(acc[ot]);
    else      ((float*)outp)[oidx] = acc[ot];
  }
}

extern "C" void kernel_launch(void* const* d_in, const int* in_sizes, int n_in,
                              void* d_out, int out_size, void* d_ws, size_t ws_size,
                              hipStream_t stream) {
  float* ws = (float*)d_ws;
  hipLaunchKernelGGL(k_detect, dim3(1), dim3(256), 0, stream,
                     (const unsigned short*)d_in[0], ws);
  hipLaunchKernelGGL(k_prep, dim3(64), dim3(256), 0, stream,
                     d_in[1], d_in[2], d_in[3], d_in[4], d_in[5],
                     d_in[6], d_in[7], d_in[8], d_in[9], d_in[10], d_in[11],
                     d_in[12], d_in[13], d_in[14], d_in[15], d_in[16],
                     d_in[17], d_in[18], d_in[19], d_in[20], ws);
  hipLaunchKernelGGL(k_zero, dim3(4206), dim3(256), 0, stream, ws);
  hipLaunchKernelGGL(k_tx,   dim3(98, 4),     dim3(256), 0, stream, d_in[0], ws);
  hipLaunchKernelGGL(k_keq,  dim3(49, 1, 4),  dim3(256), 0, stream, ws);
  hipLaunchKernelGGL(k_v,    dim3(49, 4, 4),  dim3(256), 0, stream, ws);
  hipLaunchKernelGGL(k_h,    dim3(13, 9, 4),  dim3(256), 0, stream, ws);
  hipLaunchKernelGGL(k_gram, dim3(111, 4),    dim3(256), 0, stream, ws);
  hipLaunchKernelGGL(k_stats,dim3(4),         dim3(512), 0, stream, ws);
  hipLaunchKernelGGL(k_vpq,  dim3(784),       dim3(256), 0, stream, ws);
  hipLaunchKernelGGL(k_wbox, dim3(196),       dim3(256), 0, stream, ws);
  hipLaunchKernelGGL(k_out,  dim3(196, 4, 4), dim3(64),  0, stream, ws, d_out);
}

// Round 6
// 303.886 us; speedup vs baseline: 1.3069x; 1.3069x over previous
//
#include <hip/hip_runtime.h>
#include <hip/hip_bf16.h>

typedef __hip_bfloat16 bf16;
typedef __attribute__((ext_vector_type(8))) short short8;   // 8 bf16 = 4 VGPR
typedef __attribute__((ext_vector_type(4))) float f32x4;

#define HWP 3136
#define WD 56
#define PW 58          // padded width (1-px zero border)
#define PADP 3364      // 58*58
#define CC 128
#define MIDM 32
#define OGN 512
#define NB 4

// workspace offsets in FLOAT units (all 16B-aligned)
enum : int {
  OFF_FLAG = 0,                          // [4] flag[0]: 1=bf16 inputs
  OFF_W2F  = 4,                          // fp32 [o][m] 512x32 (for stats)
  OFF_SC2  = OFF_W2F + OGN*MIDM,         // [32]
  OFF_SH2  = OFF_SC2 + MIDM,             // [32]
  OFF_B1F  = OFF_SH2 + MIDM,             // [32]
  OFF_B2F  = OFF_B1F + MIDM,             // [512]
  OFF_GNG  = OFF_B2F + OGN,              // [512]
  OFF_GNB  = OFF_GNG + OGN,              // [512]
  OFF_GPART= OFF_GNB + OGN,              // fp32 [b][64][1056] partial Gram(1024)+S1(32)
  OFF_PQ   = OFF_GPART + NB*64*1056,     // float2 [b][512]
  OFF_SS1  = OFF_PQ + NB*OGN*2,          // float2 [128] bn1 scale/shift
  OFF_SSV  = OFF_SS1 + CC*2,             // float2 [512] bnv scale/shift
  OFF_WKB  = OFF_SSV + OGN*2,            // bf16 [d][c] 128x128
  OFF_WVB  = OFF_WKB + CC*CC/2,          // bf16 [o][c] 512x128
  OFF_W1AB = OFF_WVB + OGN*CC/2,         // bf16 [m][c] 32x128
  OFF_W1BB = OFF_W1AB + MIDM*CC/2,       // bf16 [m][c] 32x128
  OFF_W2B  = OFF_W1BB + MIDM*CC/2,       // bf16 [o][m] 512x32
  OFF_HQT  = OFF_W2B + OGN*MIDM/2,       // bf16 [b][pix][m]
  OFF_GKT  = OFF_HQT + NB*HWP*MIDM/2,    // bf16 [b][pix][m]
  OFF_VT   = OFF_GKT + NB*HWP*MIDM/2,    // bf16 [b][pp PADP][o]; becomes P*v; zero border
  OFF_WQ   = OFF_VT + NB*PADP*OGN/2,     // bf16 [b][pp PADP][co]; zero border
  OFF_WSUM = OFF_WQ + NB*PADP*CC/2,      // bf16 [b][pix][co] 3x3 box of w
  OFF_R1   = OFF_WSUM + NB*HWP*CC/2,     // union region
  OFF_XT   = OFF_R1,                     // bf16 [b][pix][c]    (phase 1)
  OFF_HS   = OFF_R1,                     // bf16 [b][p][pix][m] (phase 2)
  WS_TOTAL = OFF_R1 + NB*9*HWP*MIDM/2
};

__device__ __forceinline__ float b2f(unsigned short u) {
  bf16 h; *(unsigned short*)&h = u; return __bfloat162float(h);
}
__device__ __forceinline__ unsigned short f2b(float f) {
  bf16 h = __float2bfloat16(f); return *(unsigned short*)&h;
}
__device__ __forceinline__ float ldmix(const void* p, size_t i, bool isbf) {
  return isbf ? __bfloat162float(((const bf16*)p)[i]) : ((const float*)p)[i];
}
__device__ __forceinline__ f32x4 mfma16(short8 a, short8 b, f32x4 c) {
  return __builtin_amdgcn_mfma_f32_16x16x32_bf16(a, b, c, 0, 0, 0);
}

// ---- dtype detector ----
__global__ __launch_bounds__(256) void k_detect(const unsigned short* __restrict__ xr,
                                                float* __restrict__ ws) {
  __shared__ int bad;
  if (threadIdx.x == 0) bad = 0;
  __syncthreads();
  int cnt = 0;
  for (int i = threadIdx.x; i < 16384; i += 256) {
    int e = (xr[i] >> 7) & 0xFF;
    if (e >= 141) cnt++;
  }
  atomicAdd(&bad, cnt);
  __syncthreads();
  if (threadIdx.x == 0) ws[OFF_FLAG] = (bad < 64) ? 1.f : 0.f;
}

// ---- zero padded regions (vt_pad + wq_pad, contiguous) ----
__global__ __launch_bounds__(256) void k_zero(float* __restrict__ ws) {
  const int n4 = (NB*PADP*OGN/2 + NB*PADP*CC/2) / 4;
  int i = blockIdx.x*256 + threadIdx.x;
  float4* dst = (float4*)(ws + OFF_VT);
  if (i < n4) dst[i] = make_float4(0.f, 0.f, 0.f, 0.f);
}

// ---- params: fold BN, cast weights to bf16 ----
__global__ __launch_bounds__(256) void k_prep(
    const void* __restrict__ Wk,
    const void* __restrict__ bn1_g, const void* __restrict__ bn1_b,
    const void* __restrict__ bn1_m, const void* __restrict__ bn1_v,
    const void* __restrict__ W1, const void* __restrict__ b1,
    const void* __restrict__ bn2_g, const void* __restrict__ bn2_b,
    const void* __restrict__ bn2_m, const void* __restrict__ bn2_v,
    const void* __restrict__ W2, const void* __restrict__ b2,
    const void* __restrict__ gn_g, const void* __restrict__ gn_b,
    const void* __restrict__ Wv,
    const void* __restrict__ bnv_g, const void* __restrict__ bnv_b,
    const void* __restrict__ bnv_m, const void* __restrict__ bnv_v,
    float* __restrict__ ws) {
  const bool isbf = ws[OFF_FLAG] > 0.5f;
  int tid = blockIdx.x * blockDim.x + threadIdx.x;
  int stride = gridDim.x * blockDim.x;
  unsigned short* wkb = (unsigned short*)(ws + OFF_WKB);
  unsigned short* wvb = (unsigned short*)(ws + OFF_WVB);
  unsigned short* w1ab = (unsigned short*)(ws + OFF_W1AB);
  unsigned short* w1bb = (unsigned short*)(ws + OFF_W1BB);
  unsigned short* w2b = (unsigned short*)(ws + OFF_W2B);
  float2* ss1 = (float2*)(ws + OFF_SS1);
  float2* ssv = (float2*)(ws + OFF_SSV);
  for (int i = tid; i < CC*CC; i += stride) wkb[i] = f2b(ldmix(Wk, i, isbf));
  for (int i = tid; i < OGN*CC; i += stride) wvb[i] = f2b(ldmix(Wv, i, isbf));
  for (int i = tid; i < MIDM*CC; i += stride) {
    int m = i / CC, c = i % CC;
    w1ab[i] = f2b(ldmix(W1, (size_t)m*(2*CC) + c, isbf));
    w1bb[i] = f2b(ldmix(W1, (size_t)m*(2*CC) + CC + c, isbf));
  }
  for (int i = tid; i < OGN*MIDM; i += stride) {
    float w = ldmix(W2, i, isbf);
    ws[OFF_W2F + i] = w;
    w2b[i] = f2b(w);
  }
  for (int i = tid; i < CC; i += stride) {
    float s = ldmix(bn1_g, i, isbf) / sqrtf(ldmix(bn1_v, i, isbf) + 1e-5f);
    ss1[i] = make_float2(s, ldmix(bn1_b, i, isbf) - ldmix(bn1_m, i, isbf) * s);
  }
  for (int i = tid; i < MIDM; i += stride) {
    float s = ldmix(bn2_g, i, isbf) / sqrtf(ldmix(bn2_v, i, isbf) + 1e-5f);
    ws[OFF_SC2 + i] = s;
    ws[OFF_SH2 + i] = ldmix(bn2_b, i, isbf) - ldmix(bn2_m, i, isbf) * s;
    ws[OFF_B1F + i] = ldmix(b1, i, isbf);
  }
  for (int i = tid; i < OGN; i += stride) {
    float s = ldmix(bnv_g, i, isbf) / sqrtf(ldmix(bnv_v, i, isbf) + 1e-5f);
    ssv[i] = make_float2(s, ldmix(bnv_b, i, isbf) - ldmix(bnv_m, i, isbf) * s);
    ws[OFF_B2F + i] = ldmix(b2, i, isbf);
    ws[OFF_GNG + i] = ldmix(gn_g, i, isbf);
    ws[OFF_GNB + i] = ldmix(gn_b, i, isbf);
  }
}

// ---- x -> xt[b][pix][c] bf16, LDS-tiled transpose. grid (98,4) ----
__global__ __launch_bounds__(256) void k_tx(const void* __restrict__ x,
                                            float* __restrict__ ws) {
  __shared__ unsigned short tile[32*130];
  const bool isbf = ws[OFF_FLAG] > 0.5f;
  int b = blockIdx.y, pix0 = blockIdx.x * 32;
#pragma unroll
  for (int k = 0; k < 16; k++) {
    int idx = threadIdx.x + k*256;
    int c = idx >> 5, pl = idx & 31;
    tile[pl*130 + c] = f2b(ldmix(x, ((size_t)b*CC + c)*HWP + pix0 + pl, isbf));
  }
  __syncthreads();
  unsigned short* xt = (unsigned short*)(ws + OFF_XT);
#pragma unroll
  for (int k = 0; k < 16; k++) {
    int idx = threadIdx.x + k*256;
    int c = idx & 127, pl = idx >> 7;
    xt[((size_t)b*HWP + pix0 + pl)*CC + c] = tile[pl*130 + c];
  }
}

// ---- fused: ke = relu(bn1(Wk.x)) in LDS, then hq_t/gk_t. grid (49,1,4) ----
__global__ __launch_bounds__(256, 4) void k_keq(float* __restrict__ ws) {
  __shared__ unsigned short keL[4][16][136];
  int b = blockIdx.z;
  int w = threadIdx.x >> 6, lane = threadIdx.x & 63;
  int q = lane >> 4, l16 = lane & 15;
  int pix = blockIdx.x*64 + w*16 + l16;
  const unsigned short* xt = (const unsigned short*)(ws + OFF_XT) + ((size_t)b*HWP + pix)*CC;
  short8 Bx[4];
#pragma unroll
  for (int kk = 0; kk < 4; kk++) Bx[kk] = *(const short8*)(xt + kk*32 + q*8);
  const unsigned short* wkb = (const unsigned short*)(ws + OFF_WKB);
  const float2* ss = (const float2*)(ws + OFF_SS1);
#pragma unroll
  for (int ot = 0; ot < 8; ot++) {
    int drow = ot*16 + l16;
    f32x4 c = {0.f, 0.f, 0.f, 0.f};
#pragma unroll
    for (int kk = 0; kk < 4; kk++)
      c = mfma16(*(const short8*)(wkb + (size_t)drow*CC + kk*32 + q*8), Bx[kk], c);
    int d0 = ot*16 + q*4;
    ushort4 st;
    { float2 s = ss[d0+0]; st.x = f2b(fmaxf(s.x*c[0] + s.y, 0.f)); }
    { float2 s = ss[d0+1]; st.y = f2b(fmaxf(s.x*c[1] + s.y, 0.f)); }
    { float2 s = ss[d0+2]; st.z = f2b(fmaxf(s.x*c[2] + s.y, 0.f)); }
    { float2 s = ss[d0+3]; st.w = f2b(fmaxf(s.x*c[3] + s.y, 0.f)); }
    *(ushort4*)&keL[w][l16][d0] = st;
  }
  __syncthreads();
  short8 Bk[4];
#pragma unroll
  for (int kk = 0; kk < 4; kk++) Bk[kk] = *(const short8*)&keL[w][l16][kk*32 + q*8];
  const unsigned short* w1a = (const unsigned short*)(ws + OFF_W1AB);
  const unsigned short* w1b = (const unsigned short*)(ws + OFF_W1BB);
  unsigned short* hqt = (unsigned short*)(ws + OFF_HQT) + ((size_t)b*HWP + pix)*MIDM;
  unsigned short* gkt = (unsigned short*)(ws + OFF_GKT) + ((size_t)b*HWP + pix)*MIDM;
#pragma unroll
  for (int mt = 0; mt < 2; mt++) {
    int mrow = mt*16 + l16;
    f32x4 ch = {0.f,0.f,0.f,0.f}, cg = {0.f,0.f,0.f,0.f};
#pragma unroll
    for (int kk = 0; kk < 4; kk++) {
      ch = mfma16(*(const short8*)(w1a + (size_t)mrow*CC + kk*32 + q*8), Bx[kk], ch);
      cg = mfma16(*(const short8*)(w1b + (size_t)mrow*CC + kk*32 + q*8), Bk[kk], cg);
    }
    int m0 = mt*16 + q*4;
    ushort4 sh, sg;
    sh.x = f2b(ch[0]); sh.y = f2b(ch[1]); sh.z = f2b(ch[2]); sh.w = f2b(ch[3]);
    sg.x = f2b(cg[0]); sg.y = f2b(cg[1]); sg.z = f2b(cg[2]); sg.w = f2b(cg[3]);
    *(ushort4*)(hqt + m0) = sh;
    *(ushort4*)(gkt + m0) = sg;
  }
}

// ---- v_pad[pp][o] = bnv(Wv.x) via MFMA (padded grid). grid (49,4,4) ----
__global__ __launch_bounds__(256, 4) void k_v(float* __restrict__ ws) {
  int b = blockIdx.z, by = blockIdx.y;
  int w = threadIdx.x >> 6, lane = threadIdx.x & 63;
  int q = lane >> 4, l16 = lane & 15;
  int pix = blockIdx.x*64 + w*16 + l16;
  int h0 = pix / WD, w0 = pix - h0*WD;
  int pp = (h0+1)*PW + (w0+1);
  const unsigned short* xt = (const unsigned short*)(ws + OFF_XT) + ((size_t)b*HWP + pix)*CC;
  short8 B[4];
#pragma unroll
  for (int kk = 0; kk < 4; kk++) B[kk] = *(const short8*)(xt + kk*32 + q*8);
  const unsigned short* wvb = (const unsigned short*)(ws + OFF_WVB);
  const float2* ss = (const float2*)(ws + OFF_SSV);
  unsigned short* vt = (unsigned short*)(ws + OFF_VT) + ((size_t)b*PADP + pp)*OGN;
#pragma unroll
  for (int ot = 0; ot < 8; ot++) {
    int orow = by*128 + ot*16 + l16;
    f32x4 c = {0.f, 0.f, 0.f, 0.f};
#pragma unroll
    for (int kk = 0; kk < 4; kk++)
      c = mfma16(*(const short8*)(wvb + (size_t)orow*CC + kk*32 + q*8), B[kk], c);
    int o0 = by*128 + ot*16 + q*4;
    ushort4 st;
    { float2 s = ss[o0+0]; st.x = f2b(s.x*c[0] + s.y); }
    { float2 s = ss[o0+1]; st.y = f2b(s.x*c[1] + s.y); }
    { float2 s = ss[o0+2]; st.z = f2b(s.x*c[2] + s.y); }
    { float2 s = ss[o0+3]; st.w = f2b(s.x*c[3] + s.y); }
    *(ushort4*)(vt + o0) = st;
  }
}

// ---- hs[b][p][pix][m] = relu(bn2(hq + shift(gk) + b1)). grid (13,9,4) ----
__global__ __launch_bounds__(256) void k_h(float* __restrict__ ws) {
  int b = blockIdx.z, p = blockIdx.y;
  int pix = blockIdx.x*256 + threadIdx.x;
  if (pix >= HWP) return;
  int h0 = pix / WD, w0 = pix - h0*WD;
  int nh = h0 + p/3 - 1, nw = w0 + p%3 - 1;
  bool valid = ((unsigned)nh < (unsigned)WD) && ((unsigned)nw < (unsigned)WD);
  int npix = nh*WD + nw;
  const unsigned short* hq = (const unsigned short*)(ws + OFF_HQT) + ((size_t)b*HWP + pix)*MIDM;
  const unsigned short* gk = (const unsigned short*)(ws + OFF_GKT) + ((size_t)b*HWP + npix)*MIDM;
  unsigned short* hd = (unsigned short*)(ws + OFF_HS) + ((size_t)((b*9 + p))*HWP + pix)*MIDM;
  float hv[MIDM];
#pragma unroll
  for (int k = 0; k < 4; k++) {
    short8 t = *(const short8*)(hq + k*8);
#pragma unroll
    for (int j = 0; j < 8; j++) hv[k*8+j] = b2f((unsigned short)t[j]);
  }
  if (valid) {
#pragma unroll
    for (int k = 0; k < 4; k++) {
      short8 t = *(const short8*)(gk + k*8);
#pragma unroll
      for (int j = 0; j < 8; j++) hv[k*8+j] += b2f((unsigned short)t[j]);
    }
  }
#pragma unroll
  for (int k = 0; k < 8; k++) {
    ushort4 st;
    int m = k*4;
    st.x = f2b(fmaxf(ws[OFF_SC2+m+0]*(hv[m+0] + ws[OFF_B1F+m+0]) + ws[OFF_SH2+m+0], 0.f));
    st.y = f2b(fmaxf(ws[OFF_SC2+m+1]*(hv[m+1] + ws[OFF_B1F+m+1]) + ws[OFF_SH2+m+1], 0.f));
    st.z = f2b(fmaxf(ws[OFF_SC2+m+2]*(hv[m+2] + ws[OFF_B1F+m+2]) + ws[OFF_SH2+m+2], 0.f));
    st.w = f2b(fmaxf(ws[OFF_SC2+m+3]*(hv[m+3] + ws[OFF_B1F+m+3]) + ws[OFF_SH2+m+3], 0.f));
    *(ushort4*)(hd + m) = st;
  }
}

// ---- Gram + S1, atomic-free. grid (16,4), 256 thr.
// Stage transposed tiles; frag reads are contiguous ds_read_b128. ----
__global__ __launch_bounds__(256) void k_gram(float* __restrict__ ws) {
  __shared__ unsigned short tileT[32][264];   // [m][i], stride 264 u16 (528B, 16B-aligned)
  int b = blockIdx.y, bk = blockIdx.x;
  int tid = threadIdx.x;
  int w = tid >> 6, lane = tid & 63, q = lane >> 4, l16 = lane & 15;
  const unsigned short* hsb = (const unsigned short*)(ws + OFF_HS) + (size_t)b*9*HWP*MIDM;
  const int base = bk * 1764;                 // 28224/16 rows per block
  f32x4 gLL={0,0,0,0}, gLH={0,0,0,0}, gHH={0,0,0,0}, sL={0,0,0,0}, sH={0,0,0,0};
  short8 ones;
#pragma unroll
  for (int j = 0; j < 8; j++) ones[j] = (short)0x3F80;
  const short8 zero8 = {0,0,0,0,0,0,0,0};
  for (int t = 0; t < 7; t++) {
    int r = t*256 + tid;
    bool valid = r < 1764;
    const unsigned short* src = hsb + (size_t)(base + r)*MIDM;
#pragma unroll
    for (int ch = 0; ch < 4; ch++) {
      short8 v = valid ? *(const short8*)(src + ch*8) : zero8;
#pragma unroll
      for (int j = 0; j < 8; j++) tileT[ch*8 + j][tid] = (unsigned short)v[j];
    }
    __syncthreads();
#pragma unroll
    for (int cc = 0; cc < 2; cc++) {
      int c = w*2 + cc;                       // 8 k-chunks of 32 rows
      short8 alo = *(const short8*)&tileT[l16][c*32 + q*8];
      short8 ahi = *(const short8*)&tileT[l16+16][c*32 + q*8];
      gLL = mfma16(alo, alo, gLL);
      gLH = mfma16(alo, ahi, gLH);
      gHH = mfma16(ahi, ahi, gHH);
      sL = mfma16(alo, ones, sL);
      sH = mfma16(ahi, ones, sH);
    }
    __syncthreads();
  }
  float* blob = ws + OFF_GPART + ((size_t)((b*16 + bk)*4 + w))*1056;
#pragma unroll
  for (int r = 0; r < 4; r++) {
    int row = q*4 + r;
    blob[row*32 + l16]             = gLL[r];
    blob[row*32 + 16 + l16]        = gLH[r];
    blob[(16 + l16)*32 + row]      = gLH[r];    // HL = LH^T (distinct addrs per lane)
    blob[(16 + row)*32 + 16 + l16] = gHH[r];
  }
  if (l16 == 0) {
#pragma unroll
    for (int r = 0; r < 4; r++) {
      blob[1024 + q*4 + r]      = sL[r];
      blob[1024 + 16 + q*4 + r] = sH[r];
    }
  }
}

// ---- GN stats -> PQ float2 per (b,o). grid (4) x 512 ----
__global__ __launch_bounds__(512) void k_stats(float* __restrict__ ws) {
  __shared__ float Gs[MIDM*MIDM], S1s[MIDM], saS[OGN], sqS[OGN], muS[128], invS[128];
  int b = blockIdx.x, o = threadIdx.x;
  for (int e = o; e < 1056; e += 512) {
    float s = 0.f;
    const float* pb = ws + OFF_GPART + (size_t)b*64*1056 + e;
    for (int p = 0; p < 64; p++) s += pb[(size_t)p*1056];
    if (e < 1024) Gs[e] = s; else S1s[e - 1024] = s;
  }
  __syncthreads();
  float w2[MIDM];
#pragma unroll
  for (int m = 0; m < MIDM; m++) w2[m] = ws[OFF_W2F + o*MIDM + m];
  float dotS = 0.f;
#pragma unroll
  for (int m = 0; m < MIDM; m++) dotS += w2[m] * S1s[m];
  float quad = 0.f;
  for (int a = 0; a < MIDM; a++) {
    float t = 0.f;
#pragma unroll
    for (int c = 0; c < MIDM; c++) t += Gs[a*MIDM + c] * w2[c];
    quad += w2[a] * t;
  }
  float b2o = ws[OFF_B2F + o];
  const float M = 9.f * HWP;
  saS[o] = dotS + b2o * M;
  sqS[o] = quad + 2.f*b2o*dotS + b2o*b2o*M;
  __syncthreads();
  if (o < 128) {
    float sa = saS[4*o] + saS[4*o+1] + saS[4*o+2] + saS[4*o+3];
    float sq = sqS[4*o] + sqS[4*o+1] + sqS[4*o+2] + sqS[4*o+3];
    const float invN = 1.f / (4.f * M);
    float mu = sa * invN;
    float var = sq * invN - mu*mu;
    muS[o] = mu;
    invS[o] = 1.f / sqrtf(var + 1e-5f);
  }
  __syncthreads();
  int co = o >> 2;
  float alpha = ws[OFF_GNG + o] * invS[co];
  ((float2*)(ws + OFF_PQ))[b*OGN + o] =
      make_float2(alpha, alpha*b2o + ws[OFF_GNB + o] - muS[co]*alpha);
}

// ---- vt_pad <- P*vt_pad; wq_pad[pp][co] = sum_gc Q*v. grid (784) ----
__global__ __launch_bounds__(256) void k_vpq(float* __restrict__ ws) {
  int t = blockIdx.x*256 + threadIdx.x;
  int pixg = t >> 4;
  int b = pixg / HWP, pix = pixg - b*HWP;
  int oc = (t & 15) * 32;
  int h0 = pix / WD, w0 = pix - h0*WD;
  int pp = (h0+1)*PW + (w0+1);
  unsigned short* vt = (unsigned short*)(ws + OFF_VT) + ((size_t)b*PADP + pp)*OGN + oc;
  const float2* pq = (const float2*)(ws + OFF_PQ) + b*OGN + oc;
  unsigned short* wq = (unsigned short*)(ws + OFF_WQ) + ((size_t)b*PADP + pp)*CC + (oc >> 2);
  float wacc[8];
#pragma unroll
  for (int j = 0; j < 8; j++) wacc[j] = 0.f;
#pragma unroll
  for (int ch = 0; ch < 4; ch++) {
    short8 vv = *(short8*)(vt + ch*8);
#pragma unroll
    for (int j = 0; j < 8; j++) {
      int oo = ch*8 + j;
      float v = b2f((unsigned short)vv[j]);
      float2 P = pq[oo];
      wacc[oo >> 2] += P.y * v;
      vv[j] = (short)f2b(P.x * v);
    }
    *(short8*)(vt + ch*8) = vv;
  }
  short8 st;
#pragma unroll
  for (int j = 0; j < 8; j++) st[j] = (short)f2b(wacc[j]);
  *(short8*)wq = st;
}

// ---- wsum[pix][co] = 3x3 box of wq_pad (unconditional). grid (196) ----
__global__ __launch_bounds__(256) void k_wbox(float* __restrict__ ws) {
  int t = blockIdx.x*256 + threadIdx.x;
  int pixg = t >> 2;
  int b = pixg / HWP, pix = pixg - b*HWP;
  int c0 = (t & 3) * 32;
  int h0 = pix / WD, w0 = pix - h0*WD;
  int pp0 = (h0+1)*PW + (w0+1);
  const unsigned short* wq = (const unsigned short*)(ws + OFF_WQ) + (size_t)b*PADP*CC + c0;
  float acc[32];
#pragma unroll
  for (int j = 0; j < 32; j++) acc[j] = 0.f;
#pragma unroll
  for (int p = 0; p < 9; p++) {
    int npp = pp0 + (p/3 - 1)*PW + (p%3 - 1);
    const unsigned short* row = wq + (size_t)npp*CC;
#pragma unroll
    for (int ch = 0; ch < 4; ch++) {
      short8 vv = *(const short8*)(row + ch*8);
#pragma unroll
      for (int j = 0; j < 8; j++) acc[ch*8+j] += b2f((unsigned short)vv[j]);
    }
  }
  unsigned short* dst = (unsigned short*)(ws + OFF_WSUM) + ((size_t)b*HWP + pix)*CC + c0;
#pragma unroll
  for (int ch = 0; ch < 4; ch++) {
    short8 st;
#pragma unroll
    for (int j = 0; j < 8; j++) st[j] = (short)f2b(acc[ch*8+j]);
    *(short8*)(dst + ch*8) = st;
  }
}

// ---- epilogue, branch-free: out = wsum + sum_p sum_o (W2.h)*(P*v_pad).
//     grid (196,4,4), block 64 ----
__global__ __launch_bounds__(64, 4) void k_out(const float* __restrict__ ws,
                                               void* __restrict__ outp) {
  int b = blockIdx.z, by = blockIdx.y;
  int lane = threadIdx.x;
  int q = lane >> 4, l16 = lane & 15;
  int pix = blockIdx.x*16 + l16;
  int h0 = pix / WD, w0 = pix - h0*WD;
  int pp0 = (h0+1)*PW + (w0+1);
  const bool isbf = ws[OFF_FLAG] > 0.5f;
  const unsigned short* w2b = (const unsigned short*)(ws + OFF_W2B);
  short8 A[8];
#pragma unroll
  for (int ot = 0; ot < 8; ot++) {
    int orow = by*128 + ot*16 + l16;
    A[ot] = *(const short8*)(w2b + (size_t)orow*MIDM + q*8);
  }
  const unsigned short* vtp = (const unsigned short*)(ws + OFF_VT) + (size_t)b*PADP*OGN
                              + by*128 + q*4;
  const unsigned short* hsb = (const unsigned short*)(ws + OFF_HS) + (size_t)b*9*HWP*MIDM;
  const unsigned short* wsum = (const unsigned short*)(ws + OFF_WSUM) + ((size_t)b*HWP + pix)*CC;
  float acc[8];
#pragma unroll
  for (int ot = 0; ot < 8; ot++) acc[ot] = b2f(wsum[by*32 + ot*4 + q]);
#pragma unroll
  for (int p = 0; p < 9; p++) {
    int npp = pp0 + (p/3 - 1)*PW + (p%3 - 1);
    short8 B = *(const short8*)(hsb + ((size_t)p*HWP + pix)*MIDM + q*8);
    const unsigned short* vrow = vtp + (size_t)npp*OGN;
#pragma unroll
    for (int ot = 0; ot < 8; ot++) {
      f32x4 c = {0.f, 0.f, 0.f, 0.f};
      c = mfma16(A[ot], B, c);
      ushort4 vv = *(const ushort4*)(vrow + ot*16);
      acc[ot] += c[0]*b2f(vv.x) + c[1]*b2f(vv.y) + c[2]*b2f(vv.z) + c[3]*b2f(vv.w);
    }
  }
#pragma unroll
  for (int ot = 0; ot < 8; ot++) {
    int co = by*32 + ot*4 + q;
    size_t oidx = ((size_t)b*128 + co)*HWP + pix;
    if (isbf) ((unsigned short*)outp)[oidx] = f2b(acc[ot]);
    else      ((float*)outp)[oidx] = acc[ot];
  }
}

extern "C" void kernel_launch(void* const* d_in, const int* in_sizes, int n_in,
                              void* d_out, int out_size, void* d_ws, size_t ws_size,
                              hipStream_t stream) {
  float* ws = (float*)d_ws;
  hipLaunchKernelGGL(k_detect, dim3(1), dim3(256), 0, stream,
                     (const unsigned short*)d_in[0], ws);
  hipLaunchKernelGGL(k_prep, dim3(64), dim3(256), 0, stream,
                     d_in[1], d_in[2], d_in[3], d_in[4], d_in[5],
                     d_in[6], d_in[7], d_in[8], d_in[9], d_in[10], d_in[11],
                     d_in[12], d_in[13], d_in[14], d_in[15], d_in[16],
                     d_in[17], d_in[18], d_in[19], d_in[20], ws);
  hipLaunchKernelGGL(k_zero, dim3(4206), dim3(256), 0, stream, ws);
  hipLaunchKernelGGL(k_tx,   dim3(98, 4),     dim3(256), 0, stream, d_in[0], ws);
  hipLaunchKernelGGL(k_keq,  dim3(49, 1, 4),  dim3(256), 0, stream, ws);
  hipLaunchKernelGGL(k_v,    dim3(49, 4, 4),  dim3(256), 0, stream, ws);
  hipLaunchKernelGGL(k_h,    dim3(13, 9, 4),  dim3(256), 0, stream, ws);
  hipLaunchKernelGGL(k_gram, dim3(16, 4),     dim3(256), 0, stream, ws);
  hipLaunchKernelGGL(k_stats,dim3(4),         dim3(512), 0, stream, ws);
  hipLaunchKernelGGL(k_vpq,  dim3(784),       dim3(256), 0, stream, ws);
  hipLaunchKernelGGL(k_wbox, dim3(196),       dim3(256), 0, stream, ws);
  hipLaunchKernelGGL(k_out,  dim3(196, 4, 4), dim3(64),  0, stream, ws, d_out);
}

// Round 7
// 248.636 us; speedup vs baseline: 1.5973x; 1.2222x over previous
//
#include <hip/hip_runtime.h>
#include <hip/hip_bf16.h>

typedef __hip_bfloat16 bf16;
typedef __attribute__((ext_vector_type(8))) short short8;   // 8 bf16 = 4 VGPR
typedef __attribute__((ext_vector_type(4))) float f32x4;

#define HWP 3136
#define WD 56
#define PW 58          // padded width (1-px zero border)
#define PADP 3364      // 58*58
#define CC 128
#define MIDM 32
#define OGN 512
#define NB 4

// workspace offsets in FLOAT units (all 16B-aligned)
enum : int {
  OFF_FLAG = 0,                          // [4] flag[0]: 1=bf16 inputs
  OFF_W2F  = 4,                          // fp32 [o][m] 512x32
  OFF_SC2  = OFF_W2F + OGN*MIDM,         // [32]
  OFF_SH2  = OFF_SC2 + MIDM,             // [32]
  OFF_B1F  = OFF_SH2 + MIDM,             // [32]
  OFF_B2F  = OFF_B1F + MIDM,             // [512]
  OFF_GNG  = OFF_B2F + OGN,              // [512]
  OFF_GNB  = OFF_GNG + OGN,              // [512]
  OFF_GPART= OFF_GNB + OGN,              // fp32 [b][64][1056] partial Gram+S1
  OFF_PQ   = OFF_GPART + NB*64*1056,     // float2 [b][512]
  OFF_SS1  = OFF_PQ + NB*OGN*2,          // float2 [128]
  OFF_SSV  = OFF_SS1 + CC*2,             // float2 [512]
  OFF_WKB  = OFF_SSV + OGN*2,            // bf16 [d][c] 128x128
  OFF_WVB  = OFF_WKB + CC*CC/2,          // bf16 [o][c] 512x128
  OFF_W1AB = OFF_WVB + OGN*CC/2,         // bf16 [m][c] 32x128
  OFF_W1BB = OFF_W1AB + MIDM*CC/2,       // bf16 [m][c] 32x128
  OFF_W2B  = OFF_W1BB + MIDM*CC/2,       // bf16 [o][m] 512x32
  OFF_HQT  = OFF_W2B + OGN*MIDM/2,       // bf16 [b][pix][m]
  OFF_GKT  = OFF_HQT + NB*HWP*MIDM/2,    // bf16 [b][pix][m]
  OFF_VT   = OFF_GKT + NB*HWP*MIDM/2,    // bf16 [b][pp PADP][o]; zero border
  OFF_WQ   = OFF_VT + NB*PADP*OGN/2,     // bf16 [b][pp PADP][co]; zero border
  OFF_WSUM = OFF_WQ + NB*PADP*CC/2,      // bf16 [b][pix][co] 3x3 box of wq
  OFF_R1   = OFF_WSUM + NB*HWP*CC/2,     // union region
  OFF_XT   = OFF_R1,                     // bf16 [b][pix][c]    (phase 1)
  OFF_HS   = OFF_R1,                     // bf16 [b][p][pix][m] (phase 2)
  WS_TOTAL = OFF_R1 + NB*9*HWP*MIDM/2
};

__device__ __forceinline__ float b2f(unsigned short u) {
  bf16 h; *(unsigned short*)&h = u; return __bfloat162float(h);
}
__device__ __forceinline__ unsigned short f2b(float f) {
  bf16 h = __float2bfloat16(f); return *(unsigned short*)&h;
}
__device__ __forceinline__ float ldmix(const void* p, size_t i, bool isbf) {
  return isbf ? __bfloat162float(((const bf16*)p)[i]) : ((const float*)p)[i];
}
__device__ __forceinline__ f32x4 mfma16(short8 a, short8 b, f32x4 c) {
  return __builtin_amdgcn_mfma_f32_16x16x32_bf16(a, b, c, 0, 0, 0);
}

// ---- dtype detector ----
__global__ __launch_bounds__(256) void k_detect(const unsigned short* __restrict__ xr,
                                                float* __restrict__ ws) {
  __shared__ int bad;
  if (threadIdx.x == 0) bad = 0;
  __syncthreads();
  int cnt = 0;
  for (int i = threadIdx.x; i < 16384; i += 256) {
    int e = (xr[i] >> 7) & 0xFF;
    if (e >= 141) cnt++;
  }
  atomicAdd(&bad, cnt);
  __syncthreads();
  if (threadIdx.x == 0) ws[OFF_FLAG] = (bad < 64) ? 1.f : 0.f;
}

// ---- zero only the 1-px borders of vt_pad / wq_pad. grid (912), 64 thr ----
__global__ __launch_bounds__(64) void k_zero(float* __restrict__ ws) {
  int i = blockIdx.x;                 // 0..911 = 4 b x 228 border pps
  int b = i / 228, j = i - b*228;
  int pp;
  if (j < 58)       pp = j;                       // top row
  else if (j < 116) pp = 57*PW + (j - 58);        // bottom row
  else if (j < 172) pp = (j - 116 + 1)*PW;        // left col rows 1..56
  else              pp = (j - 172 + 1)*PW + 57;   // right col rows 1..56
  const short8 z = {0,0,0,0,0,0,0,0};
  unsigned short* vt = (unsigned short*)(ws + OFF_VT) + ((size_t)b*PADP + pp)*OGN;
  *(short8*)(vt + threadIdx.x*8) = z;
  if (threadIdx.x < 16) {
    unsigned short* wq = (unsigned short*)(ws + OFF_WQ) + ((size_t)b*PADP + pp)*CC;
    *(short8*)(wq + threadIdx.x*8) = z;
  }
}

// ---- params: fold BN, cast weights to bf16 ----
__global__ __launch_bounds__(256) void k_prep(
    const void* __restrict__ Wk,
    const void* __restrict__ bn1_g, const void* __restrict__ bn1_b,
    const void* __restrict__ bn1_m, const void* __restrict__ bn1_v,
    const void* __restrict__ W1, const void* __restrict__ b1,
    const void* __restrict__ bn2_g, const void* __restrict__ bn2_b,
    const void* __restrict__ bn2_m, const void* __restrict__ bn2_v,
    const void* __restrict__ W2, const void* __restrict__ b2,
    const void* __restrict__ gn_g, const void* __restrict__ gn_b,
    const void* __restrict__ Wv,
    const void* __restrict__ bnv_g, const void* __restrict__ bnv_b,
    const void* __restrict__ bnv_m, const void* __restrict__ bnv_v,
    float* __restrict__ ws) {
  const bool isbf = ws[OFF_FLAG] > 0.5f;
  int tid = blockIdx.x * blockDim.x + threadIdx.x;
  int stride = gridDim.x * blockDim.x;
  unsigned short* wkb = (unsigned short*)(ws + OFF_WKB);
  unsigned short* wvb = (unsigned short*)(ws + OFF_WVB);
  unsigned short* w1ab = (unsigned short*)(ws + OFF_W1AB);
  unsigned short* w1bb = (unsigned short*)(ws + OFF_W1BB);
  unsigned short* w2b = (unsigned short*)(ws + OFF_W2B);
  float2* ss1 = (float2*)(ws + OFF_SS1);
  float2* ssv = (float2*)(ws + OFF_SSV);
  for (int i = tid; i < CC*CC; i += stride) wkb[i] = f2b(ldmix(Wk, i, isbf));
  for (int i = tid; i < OGN*CC; i += stride) wvb[i] = f2b(ldmix(Wv, i, isbf));
  for (int i = tid; i < MIDM*CC; i += stride) {
    int m = i / CC, c = i % CC;
    w1ab[i] = f2b(ldmix(W1, (size_t)m*(2*CC) + c, isbf));
    w1bb[i] = f2b(ldmix(W1, (size_t)m*(2*CC) + CC + c, isbf));
  }
  for (int i = tid; i < OGN*MIDM; i += stride) {
    float w = ldmix(W2, i, isbf);
    ws[OFF_W2F + i] = w;
    w2b[i] = f2b(w);
  }
  for (int i = tid; i < CC; i += stride) {
    float s = ldmix(bn1_g, i, isbf) / sqrtf(ldmix(bn1_v, i, isbf) + 1e-5f);
    ss1[i] = make_float2(s, ldmix(bn1_b, i, isbf) - ldmix(bn1_m, i, isbf) * s);
  }
  for (int i = tid; i < MIDM; i += stride) {
    float s = ldmix(bn2_g, i, isbf) / sqrtf(ldmix(bn2_v, i, isbf) + 1e-5f);
    ws[OFF_SC2 + i] = s;
    ws[OFF_SH2 + i] = ldmix(bn2_b, i, isbf) - ldmix(bn2_m, i, isbf) * s;
    ws[OFF_B1F + i] = ldmix(b1, i, isbf);
  }
  for (int i = tid; i < OGN; i += stride) {
    float s = ldmix(bnv_g, i, isbf) / sqrtf(ldmix(bnv_v, i, isbf) + 1e-5f);
    ssv[i] = make_float2(s, ldmix(bnv_b, i, isbf) - ldmix(bnv_m, i, isbf) * s);
    ws[OFF_B2F + i] = ldmix(b2, i, isbf);
    ws[OFF_GNG + i] = ldmix(gn_g, i, isbf);
    ws[OFF_GNB + i] = ldmix(gn_b, i, isbf);
  }
}

// ---- x -> xt[b][pix][c] bf16, LDS-tiled transpose. grid (98,4) ----
__global__ __launch_bounds__(256) void k_tx(const void* __restrict__ x,
                                            float* __restrict__ ws) {
  __shared__ unsigned short tile[32*130];
  const bool isbf = ws[OFF_FLAG] > 0.5f;
  int b = blockIdx.y, pix0 = blockIdx.x * 32;
#pragma unroll
  for (int k = 0; k < 16; k++) {
    int idx = threadIdx.x + k*256;
    int c = idx >> 5, pl = idx & 31;
    tile[pl*130 + c] = f2b(ldmix(x, ((size_t)b*CC + c)*HWP + pix0 + pl, isbf));
  }
  __syncthreads();
  unsigned short* xt = (unsigned short*)(ws + OFF_XT);
#pragma unroll
  for (int k = 0; k < 16; k++) {
    int idx = threadIdx.x + k*256;
    int c = idx & 127, pl = idx >> 7;
    xt[((size_t)b*HWP + pix0 + pl)*CC + c] = tile[pl*130 + c];
  }
}

// ---- fused: ke = relu(bn1(Wk.x)) in LDS, then hq_t/gk_t. grid (49,1,4) ----
__global__ __launch_bounds__(256, 4) void k_keq(float* __restrict__ ws) {
  __shared__ unsigned short keL[4][16][136];
  int b = blockIdx.z;
  int w = threadIdx.x >> 6, lane = threadIdx.x & 63;
  int q = lane >> 4, l16 = lane & 15;
  int pix = blockIdx.x*64 + w*16 + l16;
  const unsigned short* xt = (const unsigned short*)(ws + OFF_XT) + ((size_t)b*HWP + pix)*CC;
  short8 Bx[4];
#pragma unroll
  for (int kk = 0; kk < 4; kk++) Bx[kk] = *(const short8*)(xt + kk*32 + q*8);
  const unsigned short* wkb = (const unsigned short*)(ws + OFF_WKB);
  const float2* ss = (const float2*)(ws + OFF_SS1);
#pragma unroll
  for (int ot = 0; ot < 8; ot++) {
    int drow = ot*16 + l16;
    f32x4 c = {0.f, 0.f, 0.f, 0.f};
#pragma unroll
    for (int kk = 0; kk < 4; kk++)
      c = mfma16(*(const short8*)(wkb + (size_t)drow*CC + kk*32 + q*8), Bx[kk], c);
    int d0 = ot*16 + q*4;
    ushort4 st;
    { float2 s = ss[d0+0]; st.x = f2b(fmaxf(s.x*c[0] + s.y, 0.f)); }
    { float2 s = ss[d0+1]; st.y = f2b(fmaxf(s.x*c[1] + s.y, 0.f)); }
    { float2 s = ss[d0+2]; st.z = f2b(fmaxf(s.x*c[2] + s.y, 0.f)); }
    { float2 s = ss[d0+3]; st.w = f2b(fmaxf(s.x*c[3] + s.y, 0.f)); }
    *(ushort4*)&keL[w][l16][d0] = st;
  }
  __syncthreads();
  short8 Bk[4];
#pragma unroll
  for (int kk = 0; kk < 4; kk++) Bk[kk] = *(const short8*)&keL[w][l16][kk*32 + q*8];
  const unsigned short* w1a = (const unsigned short*)(ws + OFF_W1AB);
  const unsigned short* w1b = (const unsigned short*)(ws + OFF_W1BB);
  unsigned short* hqt = (unsigned short*)(ws + OFF_HQT) + ((size_t)b*HWP + pix)*MIDM;
  unsigned short* gkt = (unsigned short*)(ws + OFF_GKT) + ((size_t)b*HWP + pix)*MIDM;
#pragma unroll
  for (int mt = 0; mt < 2; mt++) {
    int mrow = mt*16 + l16;
    f32x4 ch = {0.f,0.f,0.f,0.f}, cg = {0.f,0.f,0.f,0.f};
#pragma unroll
    for (int kk = 0; kk < 4; kk++) {
      ch = mfma16(*(const short8*)(w1a + (size_t)mrow*CC + kk*32 + q*8), Bx[kk], ch);
      cg = mfma16(*(const short8*)(w1b + (size_t)mrow*CC + kk*32 + q*8), Bk[kk], cg);
    }
    int m0 = mt*16 + q*4;
    ushort4 sh, sg;
    sh.x = f2b(ch[0]); sh.y = f2b(ch[1]); sh.z = f2b(ch[2]); sh.w = f2b(ch[3]);
    sg.x = f2b(cg[0]); sg.y = f2b(cg[1]); sg.z = f2b(cg[2]); sg.w = f2b(cg[3]);
    *(ushort4*)(hqt + m0) = sh;
    *(ushort4*)(gkt + m0) = sg;
  }
}

// ---- v_pad[pp][o] = bnv(Wv.x) via MFMA (padded grid). grid (49,4,4) ----
__global__ __launch_bounds__(256, 4) void k_v(float* __restrict__ ws) {
  int b = blockIdx.z, by = blockIdx.y;
  int w = threadIdx.x >> 6, lane = threadIdx.x & 63;
  int q = lane >> 4, l16 = lane & 15;
  int pix = blockIdx.x*64 + w*16 + l16;
  int h0 = pix / WD, w0 = pix - h0*WD;
  int pp = (h0+1)*PW + (w0+1);
  const unsigned short* xt = (const unsigned short*)(ws + OFF_XT) + ((size_t)b*HWP + pix)*CC;
  short8 B[4];
#pragma unroll
  for (int kk = 0; kk < 4; kk++) B[kk] = *(const short8*)(xt + kk*32 + q*8);
  const unsigned short* wvb = (const unsigned short*)(ws + OFF_WVB);
  const float2* ss = (const float2*)(ws + OFF_SSV);
  unsigned short* vt = (unsigned short*)(ws + OFF_VT) + ((size_t)b*PADP + pp)*OGN;
#pragma unroll
  for (int ot = 0; ot < 8; ot++) {
    int orow = by*128 + ot*16 + l16;
    f32x4 c = {0.f, 0.f, 0.f, 0.f};
#pragma unroll
    for (int kk = 0; kk < 4; kk++)
      c = mfma16(*(const short8*)(wvb + (size_t)orow*CC + kk*32 + q*8), B[kk], c);
    int o0 = by*128 + ot*16 + q*4;
    ushort4 st;
    { float2 s = ss[o0+0]; st.x = f2b(s.x*c[0] + s.y); }
    { float2 s = ss[o0+1]; st.y = f2b(s.x*c[1] + s.y); }
    { float2 s = ss[o0+2]; st.z = f2b(s.x*c[2] + s.y); }
    { float2 s = ss[o0+3]; st.w = f2b(s.x*c[3] + s.y); }
    *(ushort4*)(vt + o0) = st;
  }
}

// ---- hs[b][p][pix][m] = relu(bn2(hq + shift(gk) + b1)). grid (13,9,4) ----
__global__ __launch_bounds__(256) void k_h(float* __restrict__ ws) {
  int b = blockIdx.z, p = blockIdx.y;
  int pix = blockIdx.x*256 + threadIdx.x;
  if (pix >= HWP) return;
  int h0 = pix / WD, w0 = pix - h0*WD;
  int nh = h0 + p/3 - 1, nw = w0 + p%3 - 1;
  bool valid = ((unsigned)nh < (unsigned)WD) && ((unsigned)nw < (unsigned)WD);
  int npix = nh*WD + nw;
  const unsigned short* hq = (const unsigned short*)(ws + OFF_HQT) + ((size_t)b*HWP + pix)*MIDM;
  const unsigned short* gk = (const unsigned short*)(ws + OFF_GKT) + ((size_t)b*HWP + npix)*MIDM;
  unsigned short* hd = (unsigned short*)(ws + OFF_HS) + ((size_t)((b*9 + p))*HWP + pix)*MIDM;
  float hv[MIDM];
#pragma unroll
  for (int k = 0; k < 4; k++) {
    short8 t = *(const short8*)(hq + k*8);
#pragma unroll
    for (int j = 0; j < 8; j++) hv[k*8+j] = b2f((unsigned short)t[j]);
  }
  if (valid) {
#pragma unroll
    for (int k = 0; k < 4; k++) {
      short8 t = *(const short8*)(gk + k*8);
#pragma unroll
      for (int j = 0; j < 8; j++) hv[k*8+j] += b2f((unsigned short)t[j]);
    }
  }
#pragma unroll
  for (int k = 0; k < 8; k++) {
    ushort4 st;
    int m = k*4;
    st.x = f2b(fmaxf(ws[OFF_SC2+m+0]*(hv[m+0] + ws[OFF_B1F+m+0]) + ws[OFF_SH2+m+0], 0.f));
    st.y = f2b(fmaxf(ws[OFF_SC2+m+1]*(hv[m+1] + ws[OFF_B1F+m+1]) + ws[OFF_SH2+m+1], 0.f));
    st.z = f2b(fmaxf(ws[OFF_SC2+m+2]*(hv[m+2] + ws[OFF_B1F+m+2]) + ws[OFF_SH2+m+2], 0.f));
    st.w = f2b(fmaxf(ws[OFF_SC2+m+3]*(hv[m+3] + ws[OFF_B1F+m+3]) + ws[OFF_SH2+m+3], 0.f));
    *(ushort4*)(hd + m) = st;
  }
}

// ---- Gram + S1, atomic-free. grid (16,4) ----
__global__ __launch_bounds__(256) void k_gram(float* __restrict__ ws) {
  __shared__ unsigned short tileT[32][264];
  int b = blockIdx.y, bk = blockIdx.x;
  int tid = threadIdx.x;
  int w = tid >> 6, lane = tid & 63, q = lane >> 4, l16 = lane & 15;
  const unsigned short* hsb = (const unsigned short*)(ws + OFF_HS) + (size_t)b*9*HWP*MIDM;
  const int base = bk * 1764;
  f32x4 gLL={0,0,0,0}, gLH={0,0,0,0}, gHH={0,0,0,0}, sL={0,0,0,0}, sH={0,0,0,0};
  short8 ones;
#pragma unroll
  for (int j = 0; j < 8; j++) ones[j] = (short)0x3F80;
  const short8 zero8 = {0,0,0,0,0,0,0,0};
  for (int t = 0; t < 7; t++) {
    int r = t*256 + tid;
    bool valid = r < 1764;
    const unsigned short* src = hsb + (size_t)(base + r)*MIDM;
#pragma unroll
    for (int ch = 0; ch < 4; ch++) {
      short8 v = valid ? *(const short8*)(src + ch*8) : zero8;
#pragma unroll
      for (int j = 0; j < 8; j++) tileT[ch*8 + j][tid] = (unsigned short)v[j];
    }
    __syncthreads();
#pragma unroll
    for (int cc = 0; cc < 2; cc++) {
      int c = w*2 + cc;
      short8 alo = *(const short8*)&tileT[l16][c*32 + q*8];
      short8 ahi = *(const short8*)&tileT[l16+16][c*32 + q*8];
      gLL = mfma16(alo, alo, gLL);
      gLH = mfma16(alo, ahi, gLH);
      gHH = mfma16(ahi, ahi, gHH);
      sL = mfma16(alo, ones, sL);
      sH = mfma16(ahi, ones, sH);
    }
    __syncthreads();
  }
  float* blob = ws + OFF_GPART + ((size_t)((b*16 + bk)*4 + w))*1056;
#pragma unroll
  for (int r = 0; r < 4; r++) {
    int row = q*4 + r;
    blob[row*32 + l16]             = gLL[r];
    blob[row*32 + 16 + l16]        = gLH[r];
    blob[(16 + l16)*32 + row]      = gLH[r];
    blob[(16 + row)*32 + 16 + l16] = gHH[r];
  }
  if (l16 == 0) {
#pragma unroll
    for (int r = 0; r < 4; r++) {
      blob[1024 + q*4 + r]      = sL[r];
      blob[1024 + 16 + q*4 + r] = sH[r];
    }
  }
}

// ---- GN stats -> PQ float2 per (b,o). grid (4) x 512 ----
__global__ __launch_bounds__(512) void k_stats(float* __restrict__ ws) {
  __shared__ float Gs[MIDM*MIDM], S1s[MIDM], saS[OGN], sqS[OGN], muS[128], invS[128];
  int b = blockIdx.x, o = threadIdx.x;
  for (int e = o; e < 1056; e += 512) {
    float s = 0.f;
    const float* pb = ws + OFF_GPART + (size_t)b*64*1056 + e;
    for (int p = 0; p < 64; p++) s += pb[(size_t)p*1056];
    if (e < 1024) Gs[e] = s; else S1s[e - 1024] = s;
  }
  __syncthreads();
  float w2[MIDM];
#pragma unroll
  for (int m = 0; m < MIDM; m++) w2[m] = ws[OFF_W2F + o*MIDM + m];
  float dotS = 0.f;
#pragma unroll
  for (int m = 0; m < MIDM; m++) dotS += w2[m] * S1s[m];
  float quad = 0.f;
  for (int a = 0; a < MIDM; a++) {
    float t = 0.f;
#pragma unroll
    for (int c = 0; c < MIDM; c++) t += Gs[a*MIDM + c] * w2[c];
    quad += w2[a] * t;
  }
  float b2o = ws[OFF_B2F + o];
  const float M = 9.f * HWP;
  saS[o] = dotS + b2o * M;
  sqS[o] = quad + 2.f*b2o*dotS + b2o*b2o*M;
  __syncthreads();
  if (o < 128) {
    float sa = saS[4*o] + saS[4*o+1] + saS[4*o+2] + saS[4*o+3];
    float sq = sqS[4*o] + sqS[4*o+1] + sqS[4*o+2] + sqS[4*o+3];
    const float invN = 1.f / (4.f * M);
    float mu = sa * invN;
    float var = sq * invN - mu*mu;
    muS[o] = mu;
    invS[o] = 1.f / sqrtf(var + 1e-5f);
  }
  __syncthreads();
  int co = o >> 2;
  float alpha = ws[OFF_GNG + o] * invS[co];
  ((float2*)(ws + OFF_PQ))[b*OGN + o] =
      make_float2(alpha, alpha*b2o + ws[OFF_GNB + o] - muS[co]*alpha);
}

// ---- wq_pad[pp][co] = sum_gc Q*v (vt left unscaled). grid (784) ----
__global__ __launch_bounds__(256) void k_vpq(float* __restrict__ ws) {
  int t = blockIdx.x*256 + threadIdx.x;
  int pixg = t >> 4;
  int b = pixg / HWP, pix = pixg - b*HWP;
  int oc = (t & 15) * 32;
  int h0 = pix / WD, w0 = pix - h0*WD;
  int pp = (h0+1)*PW + (w0+1);
  const unsigned short* vt = (const unsigned short*)(ws + OFF_VT) + ((size_t)b*PADP + pp)*OGN + oc;
  const float2* pq = (const float2*)(ws + OFF_PQ) + b*OGN + oc;
  unsigned short* wq = (unsigned short*)(ws + OFF_WQ) + ((size_t)b*PADP + pp)*CC + (oc >> 2);
  float wacc[8];
#pragma unroll
  for (int j = 0; j < 8; j++) wacc[j] = 0.f;
#pragma unroll
  for (int ch = 0; ch < 4; ch++) {
    short8 vv = *(const short8*)(vt + ch*8);
#pragma unroll
    for (int j = 0; j < 8; j++) {
      int oo = ch*8 + j;
      wacc[oo >> 2] += pq[oo].y * b2f((unsigned short)vv[j]);
    }
  }
  short8 st;
#pragma unroll
  for (int j = 0; j < 8; j++) st[j] = (short)f2b(wacc[j]);
  *(short8*)wq = st;
}

// ---- wsum[pix][co] = 3x3 box of wq_pad. grid (196) ----
__global__ __launch_bounds__(256) void k_wbox(float* __restrict__ ws) {
  int t = blockIdx.x*256 + threadIdx.x;
  int pixg = t >> 2;
  int b = pixg / HWP, pix = pixg - b*HWP;
  int c0 = (t & 3) * 32;
  int h0 = pix / WD, w0 = pix - h0*WD;
  int pp0 = (h0+1)*PW + (w0+1);
  const unsigned short* wq = (const unsigned short*)(ws + OFF_WQ) + (size_t)b*PADP*CC + c0;
  float acc[32];
#pragma unroll
  for (int j = 0; j < 32; j++) acc[j] = 0.f;
#pragma unroll
  for (int p = 0; p < 9; p++) {
    int npp = pp0 + (p/3 - 1)*PW + (p%3 - 1);
    const unsigned short* row = wq + (size_t)npp*CC;
#pragma unroll
    for (int ch = 0; ch < 4; ch++) {
      short8 vv = *(const short8*)(row + ch*8);
#pragma unroll
      for (int j = 0; j < 8; j++) acc[ch*8+j] += b2f((unsigned short)vv[j]);
    }
  }
  unsigned short* dst = (unsigned short*)(ws + OFF_WSUM) + ((size_t)b*HWP + pix)*CC + c0;
#pragma unroll
  for (int ch = 0; ch < 4; ch++) {
    short8 st;
#pragma unroll
    for (int j = 0; j < 8; j++) st[j] = (short)f2b(acc[ch*8+j]);
    *(short8*)(dst + ch*8) = st;
  }
}

// ---- epilogue with LDS-staged vt window.
// grid (49,4,4), 256 thr: block = 64 px strip x 128 o; 4 waves x 16 px.
// All 9-tap reads land in a contiguous padded-row-major window of <=192 pps. ----
#define VSTRIDE 136   // u16; 272 B rows: 16B-aligned, bank-spread (68 words % 32 = 4)
__global__ __launch_bounds__(256, 4) void k_out(const float* __restrict__ ws,
                                                void* __restrict__ outp) {
  __shared__ unsigned short tileV[192*VSTRIDE];
  int b = blockIdx.z, by = blockIdx.y;
  int tid = threadIdx.x;
  int w = tid >> 6, lane = tid & 63, q = lane >> 4, l16 = lane & 15;
  int pix0 = blockIdx.x*64;
  int h00 = pix0 / WD, w00 = pix0 - h00*WD;
  int wstart = (h00+1)*PW + (w00+1) - (PW+1);
  // stage 192 pps x 128 o (coalesced; overreads past pp 3363 are staged but unused)
  const unsigned short* vsrc = (const unsigned short*)(ws + OFF_VT)
      + (size_t)b*PADP*OGN + (size_t)by*128;
#pragma unroll
  for (int i = 0; i < 12; i++) {
    int u = i*256 + tid;                  // 0..3071
    int wp = u >> 4, col = (u & 15)*8;
    short8 val = *(const short8*)(vsrc + (size_t)(wstart + wp)*OGN + col);
    *(short8*)&tileV[wp*VSTRIDE + col] = val;
  }
  int pix = pix0 + w*16 + l16;
  int h0 = pix / WD, w0 = pix - h0*WD;
  int ppl = (h0+1)*PW + (w0+1) - wstart;  // local window coordinate
  const bool isbf = ws[OFF_FLAG] > 0.5f;
  // A' = P (x) W2 rows (fold GN scale into the weight fragment)
  const float2* pq = (const float2*)(ws + OFF_PQ) + b*OGN;
  short8 A[8];
#pragma unroll
  for (int ot = 0; ot < 8; ot++) {
    int orow = by*128 + ot*16 + l16;
    float P = pq[orow].x;
    const float* wrow = ws + OFF_W2F + (size_t)orow*MIDM + q*8;
    short8 a;
#pragma unroll
    for (int j = 0; j < 8; j++) a[j] = (short)f2b(P * wrow[j]);
    A[ot] = a;
  }
  const unsigned short* hsb = (const unsigned short*)(ws + OFF_HS) + (size_t)b*9*HWP*MIDM;
  const unsigned short* wsum = (const unsigned short*)(ws + OFF_WSUM) + ((size_t)b*HWP + pix)*CC;
  float acc[8];
#pragma unroll
  for (int ot = 0; ot < 8; ot++) acc[ot] = b2f(wsum[by*32 + ot*4 + q]);
  __syncthreads();
  const int doff[9] = {-PW-1, -PW, -PW+1, -1, 0, 1, PW-1, PW, PW+1};
#pragma unroll
  for (int p = 0; p < 9; p++) {
    int lp = ppl + doff[p];
    short8 B = *(const short8*)(hsb + ((size_t)p*HWP + pix)*MIDM + q*8);
    const unsigned short* vrow = &tileV[lp*VSTRIDE];
#pragma unroll
    for (int ot = 0; ot < 8; ot++) {
      f32x4 c = {0.f, 0.f, 0.f, 0.f};
      c = mfma16(A[ot], B, c);
      ushort4 vv = *(const ushort4*)(vrow + ot*16 + q*4);
      acc[ot] += c[0]*b2f(vv.x) + c[1]*b2f(vv.y) + c[2]*b2f(vv.z) + c[3]*b2f(vv.w);
    }
  }
#pragma unroll
  for (int ot = 0; ot < 8; ot++) {
    int co = by*32 + ot*4 + q;
    size_t oidx = ((size_t)b*128 + co)*HWP + pix;
    if (isbf) ((unsigned short*)outp)[oidx] = f2b(acc[ot]);
    else      ((float*)outp)[oidx] = acc[ot];
  }
}

extern "C" void kernel_launch(void* const* d_in, const int* in_sizes, int n_in,
                              void* d_out, int out_size, void* d_ws, size_t ws_size,
                              hipStream_t stream) {
  float* ws = (float*)d_ws;
  hipLaunchKernelGGL(k_detect, dim3(1), dim3(256), 0, stream,
                     (const unsigned short*)d_in[0], ws);
  hipLaunchKernelGGL(k_prep, dim3(64), dim3(256), 0, stream,
                     d_in[1], d_in[2], d_in[3], d_in[4], d_in[5],
                     d_in[6], d_in[7], d_in[8], d_in[9], d_in[10], d_in[11],
                     d_in[12], d_in[13], d_in[14], d_in[15], d_in[16],
                     d_in[17], d_in[18], d_in[19], d_in[20], ws);
  hipLaunchKernelGGL(k_zero, dim3(912),      dim3(64),  0, stream, ws);
  hipLaunchKernelGGL(k_tx,   dim3(98, 4),    dim3(256), 0, stream, d_in[0], ws);
  hipLaunchKernelGGL(k_keq,  dim3(49, 1, 4), dim3(256), 0, stream, ws);
  hipLaunchKernelGGL(k_v,    dim3(49, 4, 4), dim3(256), 0, stream, ws);
  hipLaunchKernelGGL(k_h,    dim3(13, 9, 4), dim3(256), 0, stream, ws);
  hipLaunchKernelGGL(k_gram, dim3(16, 4),    dim3(256), 0, stream, ws);
  hipLaunchKernelGGL(k_stats,dim3(4),        dim3(512), 0, stream, ws);
  hipLaunchKernelGGL(k_vpq,  dim3(784),      dim3(256), 0, stream, ws);
  hipLaunchKernelGGL(k_wbox, dim3(196),      dim3(256), 0, stream, ws);
  hipLaunchKernelGGL(k_out,  dim3(49, 4, 4), dim3(256), 0, stream, ws, d_out);
}

// Round 8
// 239.558 us; speedup vs baseline: 1.6578x; 1.0379x over previous
//
#include <hip/hip_runtime.h>
#include <hip/hip_bf16.h>

typedef __hip_bfloat16 bf16;
typedef __attribute__((ext_vector_type(8))) short short8;   // 8 bf16 = 4 VGPR
typedef __attribute__((ext_vector_type(4))) float f32x4;

#define HWP 3136
#define WD 56
#define PW 58          // padded width (1-px zero border)
#define PADP 3364      // 58*58
#define CC 128
#define MIDM 32
#define OGN 512
#define NB 4

// workspace offsets in FLOAT units (all multiples of 4 -> 16B aligned)
enum : int {
  OFF_FLAG = 0,                          // [4]
  OFF_W2F  = 4,                          // fp32 [o][m] 512x32
  OFF_SC2  = OFF_W2F + OGN*MIDM,         // [32]
  OFF_SH2  = OFF_SC2 + MIDM,             // [32]
  OFF_B1F  = OFF_SH2 + MIDM,             // [32]
  OFF_B2F  = OFF_B1F + MIDM,             // [512]
  OFF_GNG  = OFF_B2F + OGN,              // [512]
  OFF_GNB  = OFF_GNG + OGN,              // [512]
  OFF_GPART= OFF_GNB + OGN,              // fp32 [b][128][1056] Gram+S1 partials
  OFF_PQ   = OFF_GPART + NB*128*1056,    // float2 [b][512]
  OFF_SS1  = OFF_PQ + NB*OGN*2,          // float2 [128]
  OFF_SSV  = OFF_SS1 + CC*2,             // float2 [512]
  OFF_WKB  = OFF_SSV + OGN*2,            // bf16 [d][c] 128x128
  OFF_WVB  = OFF_WKB + CC*CC/2,          // bf16 [o][c] 512x128
  OFF_W1AB = OFF_WVB + OGN*CC/2,         // bf16 [m][c] 32x128
  OFF_W1BB = OFF_W1AB + MIDM*CC/2,       // bf16 [m][c] 32x128
  OFF_HQT  = OFF_W1BB + MIDM*CC/2,       // bf16 [b][pix][m] (unpadded)
  OFF_GKT  = OFF_HQT + NB*HWP*MIDM/2,    // bf16 [b][pp58][m] PADDED, zero border
  OFF_VT   = OFF_GKT + NB*PADP*MIDM/2,   // bf16 [b][pp58][o] PADDED, zero border
  OFF_R1   = OFF_VT + NB*PADP*OGN/2,     // union region
  OFF_XT   = OFF_R1,                     // bf16 [b][pix][c]    (phase 1)
  OFF_HS   = OFF_R1,                     // bf16 [b][p][pix][m] (phase 2)
  WS_TOTAL = OFF_R1 + NB*9*HWP*MIDM/2    // ~25 MB
};

__device__ __forceinline__ float b2f(unsigned short u) {
  bf16 h; *(unsigned short*)&h = u; return __bfloat162float(h);
}
__device__ __forceinline__ unsigned short f2b(float f) {
  bf16 h = __float2bfloat16(f); return *(unsigned short*)&h;
}
__device__ __forceinline__ float ldmix(const void* p, size_t i, bool isbf) {
  return isbf ? __bfloat162float(((const bf16*)p)[i]) : ((const float*)p)[i];
}
__device__ __forceinline__ f32x4 mfma16(short8 a, short8 b, f32x4 c) {
  return __builtin_amdgcn_mfma_f32_16x16x32_bf16(a, b, c, 0, 0, 0);
}
// dtype probe: bf16 N(0,s) never has bf16-exponent >= 141 (|v|>=2^14);
// fp32-as-u16 low words do ~45% of the time. Scan first 256 u16 (deterministic).
__device__ __forceinline__ bool detect_bf(const unsigned short* xr) {
  int cnt = 0;
#pragma unroll
  for (int i = 0; i < 32; i++) {
    short8 v = *(const short8*)(xr + i*8);
#pragma unroll
    for (int j = 0; j < 8; j++) {
      int e = (((unsigned short)v[j]) >> 7) & 0xFF;
      cnt += (e >= 141) ? 1 : 0;
    }
  }
  return cnt < 8;
}

// ---- L1: detect + params + x->xt transpose (blocks 0..391) + border zero ----
__global__ __launch_bounds__(256) void k_prep(
    const void* __restrict__ x,  const void* __restrict__ Wk,
    const void* __restrict__ bn1_g, const void* __restrict__ bn1_b,
    const void* __restrict__ bn1_m, const void* __restrict__ bn1_v,
    const void* __restrict__ W1, const void* __restrict__ b1,
    const void* __restrict__ bn2_g, const void* __restrict__ bn2_b,
    const void* __restrict__ bn2_m, const void* __restrict__ bn2_v,
    const void* __restrict__ W2, const void* __restrict__ b2,
    const void* __restrict__ gn_g, const void* __restrict__ gn_b,
    const void* __restrict__ Wv,
    const void* __restrict__ bnv_g, const void* __restrict__ bnv_b,
    const void* __restrict__ bnv_m, const void* __restrict__ bnv_v,
    float* __restrict__ ws) {
  __shared__ unsigned short tile[32*130];
  const bool isbf = detect_bf((const unsigned short*)x);
  int blk = blockIdx.x, tid = threadIdx.x;
  if (blk == 0 && tid == 0) ws[OFF_FLAG] = isbf ? 1.f : 0.f;
  int gid = blk*256 + tid, gstride = gridDim.x*256;
  unsigned short* wkb = (unsigned short*)(ws + OFF_WKB);
  unsigned short* wvb = (unsigned short*)(ws + OFF_WVB);
  unsigned short* w1ab = (unsigned short*)(ws + OFF_W1AB);
  unsigned short* w1bb = (unsigned short*)(ws + OFF_W1BB);
  float2* ss1 = (float2*)(ws + OFF_SS1);
  float2* ssv = (float2*)(ws + OFF_SSV);
  for (int i = gid; i < CC*CC; i += gstride) wkb[i] = f2b(ldmix(Wk, i, isbf));
  for (int i = gid; i < OGN*CC; i += gstride) wvb[i] = f2b(ldmix(Wv, i, isbf));
  for (int i = gid; i < MIDM*CC; i += gstride) {
    int m = i / CC, c = i % CC;
    w1ab[i] = f2b(ldmix(W1, (size_t)m*(2*CC) + c, isbf));
    w1bb[i] = f2b(ldmix(W1, (size_t)m*(2*CC) + CC + c, isbf));
  }
  for (int i = gid; i < OGN*MIDM; i += gstride) ws[OFF_W2F + i] = ldmix(W2, i, isbf);
  for (int i = gid; i < CC; i += gstride) {
    float s = ldmix(bn1_g, i, isbf) / sqrtf(ldmix(bn1_v, i, isbf) + 1e-5f);
    ss1[i] = make_float2(s, ldmix(bn1_b, i, isbf) - ldmix(bn1_m, i, isbf) * s);
  }
  for (int i = gid; i < MIDM; i += gstride) {
    float s = ldmix(bn2_g, i, isbf) / sqrtf(ldmix(bn2_v, i, isbf) + 1e-5f);
    ws[OFF_SC2 + i] = s;
    ws[OFF_SH2 + i] = ldmix(bn2_b, i, isbf) - ldmix(bn2_m, i, isbf) * s;
    ws[OFF_B1F + i] = ldmix(b1, i, isbf);
  }
  for (int i = gid; i < OGN; i += gstride) {
    float s = ldmix(bnv_g, i, isbf) / sqrtf(ldmix(bnv_v, i, isbf) + 1e-5f);
    ssv[i] = make_float2(s, ldmix(bnv_b, i, isbf) - ldmix(bnv_m, i, isbf) * s);
    ws[OFF_B2F + i] = ldmix(b2, i, isbf);
    ws[OFF_GNG + i] = ldmix(gn_g, i, isbf);
    ws[OFF_GNB + i] = ldmix(gn_b, i, isbf);
  }
  if (blk < 392) {
    // LDS-tiled transpose: x[b][c][pix] -> xt[b][pix][c]
    int b = blk / 98, pix0 = (blk % 98)*32;
#pragma unroll
    for (int k = 0; k < 16; k++) {
      int idx = tid + k*256;
      int c = idx >> 5, pl = idx & 31;
      tile[pl*130 + c] = f2b(ldmix(x, ((size_t)b*CC + c)*HWP + pix0 + pl, isbf));
    }
    __syncthreads();
    unsigned short* xt = (unsigned short*)(ws + OFF_XT);
#pragma unroll
    for (int k = 0; k < 16; k++) {
      int idx = tid + k*256;
      int c = idx & 127, pl = idx >> 7;
      xt[((size_t)b*HWP + pix0 + pl)*CC + c] = tile[pl*130 + c];
    }
  } else {
    // zero: vt border (912 pps x 64 o-chunks) + whole gkt_pad (4*3364*4 m-chunks)
    const int NV = 912*64, NG = NB*PADP*4;
    const short8 z = {0,0,0,0,0,0,0,0};
    unsigned short* vt = (unsigned short*)(ws + OFF_VT);
    unsigned short* gk = (unsigned short*)(ws + OFF_GKT);
    for (int u = (blk-392)*256 + tid; u < NV + NG; u += 28*256) {
      if (u < NV) {
        int bpp = u >> 6, och = u & 63;
        int b = bpp / 228, j = bpp - b*228;
        int pp;
        if (j < 58)       pp = j;
        else if (j < 116) pp = 57*PW + (j - 58);
        else if (j < 172) pp = (j - 116 + 1)*PW;
        else              pp = (j - 172 + 1)*PW + 57;
        *(short8*)(vt + ((size_t)b*PADP + pp)*OGN + och*8) = z;
      } else {
        int u2 = u - NV;
        int b = u2 / (PADP*4), rem = u2 - b*(PADP*4);
        int pp = rem >> 2, mch = rem & 3;
        *(short8*)(gk + ((size_t)b*PADP + pp)*MIDM + mch*8) = z;
      }
    }
  }
}

// ---- L2: keq (blocks 0..195) | v (blocks 196..979) ----
__global__ __launch_bounds__(256, 4) void k_mid(float* __restrict__ ws) {
  __shared__ unsigned short keL[4][16][136];
  int bid = blockIdx.x, tid = threadIdx.x;
  int w = tid >> 6, lane = tid & 63, q = lane >> 4, l16 = lane & 15;
  if (bid < 196) {
    int b = bid / 49, bx = bid - (bid/49)*49;
    int pix = bx*64 + w*16 + l16;
    const unsigned short* xt = (const unsigned short*)(ws + OFF_XT) + ((size_t)b*HWP + pix)*CC;
    short8 Bx[4];
#pragma unroll
    for (int kk = 0; kk < 4; kk++) Bx[kk] = *(const short8*)(xt + kk*32 + q*8);
    const unsigned short* wkb = (const unsigned short*)(ws + OFF_WKB);
    const float2* ss = (const float2*)(ws + OFF_SS1);
#pragma unroll
    for (int ot = 0; ot < 8; ot++) {
      int drow = ot*16 + l16;
      f32x4 c = {0.f, 0.f, 0.f, 0.f};
#pragma unroll
      for (int kk = 0; kk < 4; kk++)
        c = mfma16(*(const short8*)(wkb + (size_t)drow*CC + kk*32 + q*8), Bx[kk], c);
      int d0 = ot*16 + q*4;
      ushort4 st;
      { float2 s = ss[d0+0]; st.x = f2b(fmaxf(s.x*c[0] + s.y, 0.f)); }
      { float2 s = ss[d0+1]; st.y = f2b(fmaxf(s.x*c[1] + s.y, 0.f)); }
      { float2 s = ss[d0+2]; st.z = f2b(fmaxf(s.x*c[2] + s.y, 0.f)); }
      { float2 s = ss[d0+3]; st.w = f2b(fmaxf(s.x*c[3] + s.y, 0.f)); }
      *(ushort4*)&keL[w][l16][d0] = st;
    }
    __syncthreads();
    short8 Bk[4];
#pragma unroll
    for (int kk = 0; kk < 4; kk++) Bk[kk] = *(const short8*)&keL[w][l16][kk*32 + q*8];
    const unsigned short* w1a = (const unsigned short*)(ws + OFF_W1AB);
    const unsigned short* w1b = (const unsigned short*)(ws + OFF_W1BB);
    int h0 = pix / WD, w0 = pix - h0*WD;
    int pp = (h0+1)*PW + (w0+1);
    unsigned short* hqt = (unsigned short*)(ws + OFF_HQT) + ((size_t)b*HWP + pix)*MIDM;
    unsigned short* gkt = (unsigned short*)(ws + OFF_GKT) + ((size_t)b*PADP + pp)*MIDM;
#pragma unroll
    for (int mt = 0; mt < 2; mt++) {
      int mrow = mt*16 + l16;
      f32x4 ch = {0.f,0.f,0.f,0.f}, cg = {0.f,0.f,0.f,0.f};
#pragma unroll
      for (int kk = 0; kk < 4; kk++) {
        ch = mfma16(*(const short8*)(w1a + (size_t)mrow*CC + kk*32 + q*8), Bx[kk], ch);
        cg = mfma16(*(const short8*)(w1b + (size_t)mrow*CC + kk*32 + q*8), Bk[kk], cg);
      }
      int m0 = mt*16 + q*4;
      ushort4 sh, sg;
      sh.x = f2b(ch[0]); sh.y = f2b(ch[1]); sh.z = f2b(ch[2]); sh.w = f2b(ch[3]);
      sg.x = f2b(cg[0]); sg.y = f2b(cg[1]); sg.z = f2b(cg[2]); sg.w = f2b(cg[3]);
      *(ushort4*)(hqt + m0) = sh;
      *(ushort4*)(gkt + m0) = sg;
    }
  } else {
    int vid = bid - 196;
    int bx = vid % 49, rest = vid / 49;
    int by = rest & 3, b = rest >> 2;
    int pix = bx*64 + w*16 + l16;
    int h0 = pix / WD, w0 = pix - h0*WD;
    int pp = (h0+1)*PW + (w0+1);
    const unsigned short* xt = (const unsigned short*)(ws + OFF_XT) + ((size_t)b*HWP + pix)*CC;
    short8 B[4];
#pragma unroll
    for (int kk = 0; kk < 4; kk++) B[kk] = *(const short8*)(xt + kk*32 + q*8);
    const unsigned short* wvb = (const unsigned short*)(ws + OFF_WVB);
    const float2* ss = (const float2*)(ws + OFF_SSV);
    unsigned short* vt = (unsigned short*)(ws + OFF_VT) + ((size_t)b*PADP + pp)*OGN;
#pragma unroll
    for (int ot = 0; ot < 8; ot++) {
      int orow = by*128 + ot*16 + l16;
      f32x4 c = {0.f, 0.f, 0.f, 0.f};
#pragma unroll
      for (int kk = 0; kk < 4; kk++)
        c = mfma16(*(const short8*)(wvb + (size_t)orow*CC + kk*32 + q*8), B[kk], c);
      int o0 = by*128 + ot*16 + q*4;
      ushort4 st;
      { float2 s = ss[o0+0]; st.x = f2b(s.x*c[0] + s.y); }
      { float2 s = ss[o0+1]; st.y = f2b(s.x*c[1] + s.y); }
      { float2 s = ss[o0+2]; st.z = f2b(s.x*c[2] + s.y); }
      { float2 s = ss[o0+3]; st.w = f2b(s.x*c[3] + s.y); }
      *(ushort4*)(vt + o0) = st;
    }
  }
}

// ---- L3: h recompute + hs write + Gram/S1 partials. grid (32,4) ----
__global__ __launch_bounds__(256) void k_gramh(float* __restrict__ ws) {
  __shared__ unsigned short tileT[32][264];
  int b = blockIdx.y, bk = blockIdx.x;
  int tid = threadIdx.x;
  int w = tid >> 6, lane = tid & 63, q = lane >> 4, l16 = lane & 15;
  const int base = bk * 882;                 // 28224 / 32
  const unsigned short* hqt = (const unsigned short*)(ws + OFF_HQT) + (size_t)b*HWP*MIDM;
  const unsigned short* gkp = (const unsigned short*)(ws + OFF_GKT) + (size_t)b*PADP*MIDM;
  unsigned short* hsb = (unsigned short*)(ws + OFF_HS) + (size_t)b*9*HWP*MIDM;
  float sc2[MIDM], bas0[MIDM];
#pragma unroll
  for (int m = 0; m < MIDM; m++) {
    sc2[m] = ws[OFF_SC2 + m];
    bas0[m] = sc2[m]*ws[OFF_B1F + m] + ws[OFF_SH2 + m];
  }
  f32x4 gLL={0,0,0,0}, gLH={0,0,0,0}, gHH={0,0,0,0}, sL={0,0,0,0}, sH={0,0,0,0};
  short8 ones;
#pragma unroll
  for (int j = 0; j < 8; j++) ones[j] = (short)0x3F80;
  for (int t = 0; t < 4; t++) {
    int r = t*256 + tid;
    bool valid = r < 882;
    int R = valid ? (base + r) : 0;
    int p = R / HWP, pix = R - p*HWP;
    int h0 = pix / WD, w0 = pix - h0*WD;
    int npp = (h0 + p/3)*PW + (w0 + p - (p/3)*3);
    const unsigned short* hq = hqt + (size_t)pix*MIDM;
    const unsigned short* gk = gkp + (size_t)npp*MIDM;
    short8 hb[4];
#pragma unroll
    for (int ch = 0; ch < 4; ch++) {
      short8 th = *(const short8*)(hq + ch*8);
      short8 tg = *(const short8*)(gk + ch*8);
      short8 o;
#pragma unroll
      for (int j = 0; j < 8; j++) {
        int m = ch*8 + j;
        float hv = b2f((unsigned short)th[j]) + b2f((unsigned short)tg[j]);
        float v = fmaxf(sc2[m]*hv + bas0[m], 0.f);
        o[j] = valid ? (short)f2b(v) : (short)0;
      }
      hb[ch] = o;
      if (valid) *(short8*)(hsb + (size_t)R*MIDM + ch*8) = o;
#pragma unroll
      for (int j = 0; j < 8; j++) tileT[ch*8 + j][tid] = (unsigned short)o[j];
    }
    __syncthreads();
#pragma unroll
    for (int cc = 0; cc < 2; cc++) {
      int c = w*2 + cc;
      short8 alo = *(const short8*)&tileT[l16][c*32 + q*8];
      short8 ahi = *(const short8*)&tileT[l16+16][c*32 + q*8];
      gLL = mfma16(alo, alo, gLL);
      gLH = mfma16(alo, ahi, gLH);
      gHH = mfma16(ahi, ahi, gHH);
      sL = mfma16(alo, ones, sL);
      sH = mfma16(ahi, ones, sH);
    }
    __syncthreads();
  }
  float* blob = ws + OFF_GPART + ((size_t)((b*32 + bk)*4 + w))*1056;
#pragma unroll
  for (int r = 0; r < 4; r++) {
    int row = q*4 + r;
    blob[row*32 + l16]             = gLL[r];
    blob[row*32 + 16 + l16]        = gLH[r];
    blob[(16 + l16)*32 + row]      = gLH[r];   // HL = LH^T
    blob[(16 + row)*32 + 16 + l16] = gHH[r];
  }
  if (l16 == 0) {
#pragma unroll
    for (int r = 0; r < 4; r++) {
      blob[1024 + q*4 + r]      = sL[r];
      blob[1024 + 16 + q*4 + r] = sH[r];
    }
  }
}

// ---- L4: GN stats -> PQ. grid (4) x 512 ----
__global__ __launch_bounds__(512) void k_stats(float* __restrict__ ws) {
  __shared__ float Gs[MIDM*MIDM], S1s[MIDM], saS[OGN], sqS[OGN], muS[128], invS[128];
  int b = blockIdx.x, o = threadIdx.x;
  for (int e = o; e < 1056; e += 512) {
    float s = 0.f;
    const float* pb = ws + OFF_GPART + (size_t)b*128*1056 + e;
    for (int p = 0; p < 128; p++) s += pb[(size_t)p*1056];
    if (e < 1024) Gs[e] = s; else S1s[e - 1024] = s;
  }
  __syncthreads();
  float w2[MIDM];
#pragma unroll
  for (int m = 0; m < MIDM; m++) w2[m] = ws[OFF_W2F + o*MIDM + m];
  float dotS = 0.f;
#pragma unroll
  for (int m = 0; m < MIDM; m++) dotS += w2[m] * S1s[m];
  float quad = 0.f;
  for (int a = 0; a < MIDM; a++) {
    float t = 0.f;
#pragma unroll
    for (int c = 0; c < MIDM; c++) t += Gs[a*MIDM + c] * w2[c];
    quad += w2[a] * t;
  }
  float b2o = ws[OFF_B2F + o];
  const float M = 9.f * HWP;
  saS[o] = dotS + b2o * M;
  sqS[o] = quad + 2.f*b2o*dotS + b2o*b2o*M;
  __syncthreads();
  if (o < 128) {
    float sa = saS[4*o] + saS[4*o+1] + saS[4*o+2] + saS[4*o+3];
    float sq = sqS[4*o] + sqS[4*o+1] + sqS[4*o+2] + sqS[4*o+3];
    const float invN = 1.f / (4.f * M);
    float mu = sa * invN;
    float var = sq * invN - mu*mu;
    muS[o] = mu;
    invS[o] = 1.f / sqrtf(var + 1e-5f);
  }
  __syncthreads();
  int co = o >> 2;
  float alpha = ws[OFF_GNG + o] * invS[co];
  ((float2*)(ws + OFF_PQ))[b*OGN + o] =
      make_float2(alpha, alpha*b2o + ws[OFF_GNB + o] - muS[co]*alpha);
}

// ---- L5: epilogue. out = sum_p sum_o ((P.W2).h + Q) * v_pad, LDS-staged vt.
//      grid (49,4,4), 256 thr ----
#define VSTRIDE 136
__global__ __launch_bounds__(256, 3) void k_out(const float* __restrict__ ws,
                                                void* __restrict__ outp) {
  __shared__ unsigned short tileV[192*VSTRIDE];
  int b = blockIdx.z, by = blockIdx.y;
  int tid = threadIdx.x;
  int w = tid >> 6, lane = tid & 63, q = lane >> 4, l16 = lane & 15;
  int pix0 = blockIdx.x*64;
  int h00 = pix0 / WD, w00 = pix0 - h00*WD;
  int wstart = (h00+1)*PW + (w00+1) - (PW+1);
  const unsigned short* vsrc = (const unsigned short*)(ws + OFF_VT)
      + (size_t)b*PADP*OGN + (size_t)by*128;
#pragma unroll
  for (int i = 0; i < 12; i++) {
    int u = i*256 + tid;
    int wp = u >> 4, col = (u & 15)*8;
    short8 val = *(const short8*)(vsrc + (size_t)(wstart + wp)*OGN + col);
    *(short8*)&tileV[wp*VSTRIDE + col] = val;
  }
  int pix = pix0 + w*16 + l16;
  int h0 = pix / WD, w0 = pix - h0*WD;
  int ppl = (h0+1)*PW + (w0+1) - wstart;
  const bool isbf = ws[OFF_FLAG] > 0.5f;
  const float2* pq = (const float2*)(ws + OFF_PQ) + b*OGN;
  short8 A[8];
  f32x4 Qv[8];
#pragma unroll
  for (int ot = 0; ot < 8; ot++) {
    int orow = by*128 + ot*16 + l16;
    float P = pq[orow].x;
    const float* wrow = ws + OFF_W2F + (size_t)orow*MIDM + q*8;
    short8 a;
#pragma unroll
    for (int j = 0; j < 8; j++) a[j] = (short)f2b(P * wrow[j]);
    A[ot] = a;
    int o0 = by*128 + ot*16 + q*4;
    f32x4 qv = { pq[o0+0].y, pq[o0+1].y, pq[o0+2].y, pq[o0+3].y };
    Qv[ot] = qv;
  }
  const unsigned short* hsb = (const unsigned short*)(ws + OFF_HS) + (size_t)b*9*HWP*MIDM;
  float acc[8];
#pragma unroll
  for (int ot = 0; ot < 8; ot++) acc[ot] = 0.f;
  __syncthreads();
  const int doff[9] = {-PW-1, -PW, -PW+1, -1, 0, 1, PW-1, PW, PW+1};
#pragma unroll
  for (int p = 0; p < 9; p++) {
    int lp = ppl + doff[p];
    short8 B = *(const short8*)(hsb + ((size_t)p*HWP + pix)*MIDM + q*8);
    const unsigned short* vrow = &tileV[lp*VSTRIDE];
#pragma unroll
    for (int ot = 0; ot < 8; ot++) {
      f32x4 c = {0.f, 0.f, 0.f, 0.f};
      c = mfma16(A[ot], B, c);
      ushort4 vv = *(const ushort4*)(vrow + ot*16 + q*4);
      acc[ot] += (c[0] + Qv[ot][0])*b2f(vv.x) + (c[1] + Qv[ot][1])*b2f(vv.y)
               + (c[2] + Qv[ot][2])*b2f(vv.z) + (c[3] + Qv[ot][3])*b2f(vv.w);
    }
  }
#pragma unroll
  for (int ot = 0; ot < 8; ot++) {
    int co = by*32 + ot*4 + q;
    size_t oidx = ((size_t)b*128 + co)*HWP + pix;
    if (isbf) ((unsigned short*)outp)[oidx] = f2b(acc[ot]);
    else      ((float*)outp)[oidx] = acc[ot];
  }
}

extern "C" void kernel_launch(void* const* d_in, const int* in_sizes, int n_in,
                              void* d_out, int out_size, void* d_ws, size_t ws_size,
                              hipStream_t stream) {
  float* ws = (float*)d_ws;
  hipLaunchKernelGGL(k_prep, dim3(420), dim3(256), 0, stream,
                     d_in[0], d_in[1], d_in[2], d_in[3], d_in[4], d_in[5],
                     d_in[6], d_in[7], d_in[8], d_in[9], d_in[10], d_in[11],
                     d_in[12], d_in[13], d_in[14], d_in[15], d_in[16],
                     d_in[17], d_in[18], d_in[19], d_in[20], ws);
  hipLaunchKernelGGL(k_mid,  dim3(980),      dim3(256), 0, stream, ws);
  hipLaunchKernelGGL(k_gramh,dim3(32, 4),    dim3(256), 0, stream, ws);
  hipLaunchKernelGGL(k_stats,dim3(4),        dim3(512), 0, stream, ws);
  hipLaunchKernelGGL(k_out,  dim3(49, 4, 4), dim3(256), 0, stream, ws, d_out);
}